// Round 4
// baseline (670.758 us; speedup 1.0000x reference)
//
#include <hip/hip_runtime.h>
#include <math.h>

#define BB 256
#define TT 512
#define KK 128
#define AIDX(i) ((i) + (((i) >> 5) << 2))

typedef float v2f __attribute__((ext_vector_type(2)));
typedef unsigned short u16v2 __attribute__((ext_vector_type(2)));

template<int CTRL>
__device__ __forceinline__ int dpp_i(int x) {
  return __builtin_amdgcn_update_dpp(x, x, CTRL, 0xF, 0xF, true);
}
template<int CTRL>
__device__ __forceinline__ float dpp_f(float x) {
  return __int_as_float(dpp_i<CTRL>(__float_as_int(x)));
}
__device__ __forceinline__ float swz16_f(float x) {
  return __int_as_float(__builtin_amdgcn_ds_swizzle(__float_as_int(x), 0x401F));
}
__device__ __forceinline__ int pkminu16(int a, int b) {
  u16v2 av = *(u16v2*)&a, bv = *(u16v2*)&b;
  u16v2 r = __builtin_elementwise_min(av, bv);
  return *(int*)&r;
}
// barrier that drains LDS only (not vmcnt) — keeps prefetch loads in flight
#define BARRIER_LGKM() asm volatile("s_waitcnt lgkmcnt(0)\ns_barrier" ::: "memory")

// ============================================================================
// NEW PATH phase 1: viterbi WITHOUT argmax scan (alphas streamed to global)
// + forward (log-norm) unchanged. 512 blocks x 512 threads.
// ============================================================================
__global__ __launch_bounds__(512, 4) void crf_fwd(
    const float* __restrict__ logits,     // [B,T,K]
    const int* __restrict__ labels,       // [B,T]
    const int* __restrict__ seq_lens,     // [B]
    const float* __restrict__ trans,      // [K,K]
    float* __restrict__ negll,            // [B] in ws
    int* __restrict__ lastIdx,            // [B] in ws
    float* __restrict__ alphaOut)         // [B][T][K] in ws
{
  const int tid = threadIdx.x;
  const int cg = tid >> 3, rg = tid & 7;
  const int j0 = cg * 2, i0 = rg * 16;

  if (blockIdx.x < BB) {
    // ================= VITERBI (scan-free) =================
    const int b = blockIdx.x;
    const int L = seq_lens[b];
    __shared__ __align__(16) float av[2][144];
    __shared__ float rv[8]; __shared__ int ri[8];

    v2f tv[16];
#pragma unroll
    for (int ii = 0; ii < 16; ++ii)
      tv[ii] = *(const v2f*)&trans[(i0 + ii) * KK + j0];

    if (tid < KK) {
      float l0 = logits[(b * TT) * KK + tid];
      av[0][AIDX(tid)] = l0;
      alphaOut[(b * TT) * KK + tid] = l0;     // alpha_0
    }

    v2f emC[4], emN[4];
#pragma unroll
    for (int s = 0; s < 4; ++s) {
      int t2 = 1 + s; if (t2 > L - 1) t2 = (L > 1) ? (L - 1) : 0;
      emC[s] = *(const v2f*)&logits[(b * TT + t2) * KK + j0];
    }
    __syncthreads();

    for (int tc = 1; tc < L; tc += 4) {
#pragma unroll
      for (int s = 0; s < 4; ++s) {
        int t2 = tc + 4 + s; if (t2 > L - 1) t2 = L - 1;
        emN[s] = *(const v2f*)&logits[(b * TT + t2) * KK + j0];
      }
#pragma unroll
      for (int s = 0; s < 4; ++s) {
        const int t = tc + s;
        if (t >= L) break;
        const float4* avr = (const float4*)(av[(t & 1) ^ 1] + AIDX(i0));
        v2f sv[16];
#pragma unroll
        for (int q = 0; q < 4; ++q) {
          float4 a4 = avr[q];
#pragma unroll
          for (int c = 0; c < 4; ++c) {
            float a = (c == 0) ? a4.x : (c == 1) ? a4.y : (c == 2) ? a4.z : a4.w;
            sv[q * 4 + c] = (v2f){a, a} + tv[q * 4 + c];   // exact IEEE adds
          }
        }
        // in-thread max tree (exact; max order-insensitive)
        v2f m;
        {
          v2f m0 = __builtin_elementwise_max(sv[0], sv[1]);
          v2f m1 = __builtin_elementwise_max(sv[2], sv[3]);
          v2f m2 = __builtin_elementwise_max(sv[4], sv[5]);
          v2f m3 = __builtin_elementwise_max(sv[6], sv[7]);
          v2f m4 = __builtin_elementwise_max(sv[8], sv[9]);
          v2f m5 = __builtin_elementwise_max(sv[10], sv[11]);
          v2f m6 = __builtin_elementwise_max(sv[12], sv[13]);
          v2f m7 = __builtin_elementwise_max(sv[14], sv[15]);
          m0 = __builtin_elementwise_max(m0, m1);
          m2 = __builtin_elementwise_max(m2, m3);
          m4 = __builtin_elementwise_max(m4, m5);
          m6 = __builtin_elementwise_max(m6, m7);
          m0 = __builtin_elementwise_max(m0, m2);
          m4 = __builtin_elementwise_max(m4, m6);
          m = __builtin_elementwise_max(m0, m4);
        }
        // cross-row-group max: xor1, xor2, xor4 — all DPP
        {
          v2f o;
          o.x = dpp_f<0xB1>(m.x); o.y = dpp_f<0xB1>(m.y);
          m = __builtin_elementwise_max(m, o);
          o.x = dpp_f<0x4E>(m.x); o.y = dpp_f<0x4E>(m.y);
          m = __builtin_elementwise_max(m, o);
          o.x = dpp_f<0x141>(m.x); o.y = dpp_f<0x141>(m.y);
          m = __builtin_elementwise_max(m, o);
        }
        v2f nav = m + emC[s];
        if (rg == 0) {
          *(v2f*)(av[t & 1] + AIDX(j0)) = nav;
          *(v2f*)&alphaOut[(b * TT + t) * KK + j0] = nav;  // stream alpha_t
        }
        BARRIER_LGKM();
      }
#pragma unroll
      for (int s = 0; s < 4; ++s) emC[s] = emN[s];
    }

    // final argmax across K → lastIdx
    const float* avf = av[(L - 1) & 1];
    {
      float v = (tid < KK) ? avf[AIDX(tid)] : -3.4e38f;
      int idx = (tid < KK) ? tid : KK;
#pragma unroll
      for (int mm = 1; mm < 64; mm <<= 1) {
        float ov = __shfl_xor(v, mm);
        int oi = __shfl_xor(idx, mm);
        if (ov > v || (ov == v && oi < idx)) { v = ov; idx = oi; }
      }
      if ((tid & 63) == 0) { rv[tid >> 6] = v; ri[tid >> 6] = idx; }
    }
    __syncthreads();
    if (tid == 0) {
      float bv = rv[0]; int bi = ri[0];
#pragma unroll
      for (int w = 1; w < 8; ++w)
        if (rv[w] > bv || (rv[w] == bv && ri[w] < bi)) { bv = rv[w]; bi = ri[w]; }
      lastIdx[b] = bi;
    }

  } else {
    // ================= FORWARD (log-norm) — unchanged from 438us baseline ===
    const int b = blockIdx.x - BB;
    const int L = seq_lens[b];
    __shared__ __align__(16) float ev[2][144];
    __shared__ __align__(16) float wmax[16];
    __shared__ float rs[8]; __shared__ float rsc[8];

    v2f tw[16];
#pragma unroll
    for (int ii = 0; ii < 16; ++ii) {
      v2f tr = *(const v2f*)&trans[(i0 + ii) * KK + j0];
      tw[ii].x = __expf(tr.x);
      tw[ii].y = __expf(tr.y);
    }
    if (tid < KK) ev[0][AIDX(tid)] = __expf(logits[(b * TT) * KK + tid]);
    if (tid < 16) wmax[tid] = 1.0f;

    v2f emC[4], emN[4];
#pragma unroll
    for (int s = 0; s < 4; ++s) {
      int t2 = 1 + s; if (t2 > L - 1) t2 = (L > 1) ? (L - 1) : 0;
      emC[s] = *(const v2f*)&logits[(b * TT + t2) * KK + j0];
    }
    __syncthreads();

    float Cln = 0.0f;
    for (int tc = 1; tc < L; tc += 4) {
#pragma unroll
      for (int s = 0; s < 4; ++s) {
        int t2 = tc + 4 + s; if (t2 > L - 1) t2 = L - 1;
        emN[s] = *(const v2f*)&logits[(b * TT + t2) * KK + j0];
      }
      // renorm factor (exact pow2), once per 4-step chunk
      float r;
      {
        float4 w0 = *(const float4*)&wmax[0];
        float4 w1 = *(const float4*)&wmax[4];
        float4 w2 = *(const float4*)&wmax[8];
        float4 w3 = *(const float4*)&wmax[12];
        float U = fmaxf(fmaxf(fmaxf(w0.x, w0.y), fmaxf(w0.z, w0.w)),
                        fmaxf(fmaxf(w1.x, w1.y), fmaxf(w1.z, w1.w)));
        U = fmaxf(U, fmaxf(fmaxf(fmaxf(w2.x, w2.y), fmaxf(w2.z, w2.w)),
                           fmaxf(fmaxf(w3.x, w3.y), fmaxf(w3.z, w3.w))));
        int ex = (__float_as_int(U) >> 23) & 255;
        r = __int_as_float((254 - ex) << 23);
        Cln += (float)(ex - 127) * 0.6931471805599453f;
      }
#pragma unroll
      for (int s = 0; s < 4; ++s) {
        const int t = tc + s;
        if (t >= L) break;
        const float4* evr = (const float4*)(ev[(t & 1) ^ 1] + AIDX(i0));
        v2f S2 = {0.0f, 0.0f};
#pragma unroll
        for (int q = 0; q < 4; ++q) {
          float4 e4 = evr[q];
#pragma unroll
          for (int c = 0; c < 4; ++c) {
            float e = (c == 0) ? e4.x : (c == 1) ? e4.y : (c == 2) ? e4.z : e4.w;
            S2 += (v2f){e, e} * tw[q * 4 + c];   // pk_fma
          }
        }
        {
          v2f o;
          o.x = dpp_f<0xB1>(S2.x); o.y = dpp_f<0xB1>(S2.y); S2 += o;
          o.x = dpp_f<0x4E>(S2.x); o.y = dpp_f<0x4E>(S2.y); S2 += o;
          o.x = dpp_f<0x141>(S2.x); o.y = dpp_f<0x141>(S2.y); S2 += o;
        }
        v2f em2 = emC[s];
        float evn0 = S2.x * __expf(em2.x);
        float evn1 = S2.y * __expf(em2.y);
        if (s == 0) { evn0 *= r; evn1 *= r; }
        if (rg == 0)
          *(v2f*)(ev[t & 1] + AIDX(j0)) = (v2f){evn0, evn1};
        if (s == 3) {
          float wm = fmaxf(evn0, evn1);
          wm = fmaxf(wm, dpp_f<0x140>(wm));   // xor8 (values 8-uniform)
          wm = fmaxf(wm, swz16_f(wm));        // xor16
          if ((tid & 31) == 0) wmax[tid >> 5] = wm;
        }
        BARRIER_LGKM();
      }
#pragma unroll
      for (int s = 0; s < 4; ++s) emC[s] = emN[s];
    }

    const float* evf = ev[(L - 1) & 1];
    {
      float ssum = (tid < KK) ? evf[AIDX(tid)] : 0.0f;
#pragma unroll
      for (int mm = 1; mm < 64; mm <<= 1) ssum += __shfl_xor(ssum, mm);
      if ((tid & 63) == 0) rs[tid >> 6] = ssum;
    }
    float sc = 0.0f;
    for (int tt2 = tid; tt2 < L; tt2 += 512) {
      int lab = labels[b * TT + tt2];
      sc += logits[(b * TT + tt2) * KK + lab];
      if (tt2 >= 1) sc += trans[labels[b * TT + tt2 - 1] * KK + lab];
    }
#pragma unroll
    for (int mm = 1; mm < 64; mm <<= 1) sc += __shfl_xor(sc, mm);
    if ((tid & 63) == 0) rsc[tid >> 6] = sc;
    __syncthreads();
    if (tid == 0) {
      float es = rs[0]; float scf = rsc[0];
#pragma unroll
      for (int w = 1; w < 8; ++w) { es += rs[w]; scf += rsc[w]; }
      negll[b] = (Cln + logf(es)) - scf;
    }
  }
}

// ============================================================================
// NEW PATH phase 2: backtrack by recomputing the single argmax column per step.
// One wave per sequence. trans transposed into LDS; alpha prefetched 2 ahead.
// tag_t = argmax_i(alpha_t[i] + trans[i][tag_{t+1}]) — bit-exact adds,
// first-index tie-break (matches jnp.argmax).
// ============================================================================
__global__ __launch_bounds__(64, 1) void crf_backtrack(
    const float* __restrict__ alpha,      // [B][T][K] in ws
    const int* __restrict__ seq_lens,     // [B]
    const int* __restrict__ lastIdx,      // [B] in ws
    const float* __restrict__ trans,      // [K,K]
    float* __restrict__ pred_out)         // [B,T] as float
{
  const int b = blockIdx.x, l = threadIdx.x;
  const int L = seq_lens[b];
  __shared__ float tT[KK][KK + 2];        // transposed trans; row stride 520B (8-aligned)
  __shared__ float tagsf[TT];

  // build transpose (one-time; ~8-way write conflicts acceptable)
  for (int i = 0; i < KK; ++i) {
    v2f r = *(const v2f*)&trans[i * KK + 2 * l];
    tT[2 * l][i] = r.x;
    tT[2 * l + 1][i] = r.y;
  }
  const int last = lastIdx[b];
  for (int t = l; t < TT; t += 64) tagsf[t] = (float)last;   // t >= L-1 keep this
  __syncthreads();

  if (L >= 2) {
    int tag = last;
    // prefetch 2 steps of alpha
    v2f aC = *(const v2f*)&alpha[(b * TT + (L - 2)) * KK + 2 * l];
    v2f aN = (L >= 3) ? *(const v2f*)&alpha[(b * TT + (L - 3)) * KK + 2 * l] : aC;
    for (int t = L - 2; t >= 0; --t) {
      v2f aNN;
      if (t >= 2) aNN = *(const v2f*)&alpha[(b * TT + (t - 2)) * KK + 2 * l];
      v2f col = *(const v2f*)&tT[tag][2 * l];    // ds_read_b64, conflict-light
      v2f sv = aC + col;                          // exact IEEE adds
      float v; int idx;
      if (sv.x >= sv.y) { v = sv.x; idx = 2 * l; }      // first-index within pair
      else              { v = sv.y; idx = 2 * l + 1; }
#pragma unroll
      for (int mm = 1; mm < 64; mm <<= 1) {
        float ov = __shfl_xor(v, mm);
        int oi = __shfl_xor(idx, mm);
        if (ov > v || (ov == v && oi < idx)) { v = ov; idx = oi; }
      }
      tag = idx;                                  // uniform across lanes
      if (l == 0) tagsf[t] = (float)tag;
      aC = aN; aN = aNN;
    }
  }
  __syncthreads();
#pragma unroll
  for (int k = 0; k < 8; ++k)
    pred_out[b * TT + l * 8 + k] = tagsf[l * 8 + k];
}

// ============================================================================
// FALLBACK: verbatim 438us two-block kernel (bp in ws), used if ws too small.
// ============================================================================
__global__ __launch_bounds__(512, 4) void crf_main_fb(
    const float* __restrict__ logits,
    const int* __restrict__ labels,
    const int* __restrict__ seq_lens,
    const float* __restrict__ trans,
    float* __restrict__ pred_out,
    float* __restrict__ negll,
    unsigned char* __restrict__ bp)
{
  const int tid = threadIdx.x;
  const int cg = tid >> 3, rg = tid & 7;
  const int j0 = cg * 2, i0 = rg * 16;

  if (blockIdx.x < BB) {
    const int b = blockIdx.x;
    const int L = seq_lens[b];
    __shared__ __align__(16) float av[2][144];
    __shared__ unsigned char tags[TT];
    __shared__ float rv[8]; __shared__ int ri[8];
    __shared__ int last_s;

    v2f tv[16];
#pragma unroll
    for (int ii = 0; ii < 16; ++ii)
      tv[ii] = *(const v2f*)&trans[(i0 + ii) * KK + j0];

    if (tid < KK) av[0][AIDX(tid)] = logits[(b * TT) * KK + tid];

    v2f emC[4], emN[4];
#pragma unroll
    for (int s = 0; s < 4; ++s) {
      int t2 = 1 + s; if (t2 > L - 1) t2 = (L > 1) ? (L - 1) : 0;
      emC[s] = *(const v2f*)&logits[(b * TT + t2) * KK + j0];
    }
    __syncthreads();

    unsigned int pw0 = 0, pw1 = 0; int pend_c = -1;

    for (int tc = 1; tc < L; tc += 4) {
#pragma unroll
      for (int s = 0; s < 4; ++s) {
        int t2 = tc + 4 + s; if (t2 > L - 1) t2 = L - 1;
        emN[s] = *(const v2f*)&logits[(b * TT + t2) * KK + j0];
      }
      if (pend_c >= 0 && rg == 1) {
        *(uint2*)(bp + (((b << 7) + pend_c) << 9) + (cg << 3)) =
            make_uint2(pw0, pw1);
      }
      unsigned int w0 = 0, w1 = 0;
#pragma unroll
      for (int s = 0; s < 4; ++s) {
        const int t = tc + s;
        if (t >= L) break;
        const float4* avr = (const float4*)(av[(t & 1) ^ 1] + AIDX(i0));
        v2f sv[16];
#pragma unroll
        for (int q = 0; q < 4; ++q) {
          float4 a4 = avr[q];
#pragma unroll
          for (int c = 0; c < 4; ++c) {
            float a = (c == 0) ? a4.x : (c == 1) ? a4.y : (c == 2) ? a4.z : a4.w;
            sv[q * 4 + c] = (v2f){a, a} + tv[q * 4 + c];
          }
        }
        v2f m;
        {
          v2f m0 = __builtin_elementwise_max(sv[0], sv[1]);
          v2f m1 = __builtin_elementwise_max(sv[2], sv[3]);
          v2f m2 = __builtin_elementwise_max(sv[4], sv[5]);
          v2f m3 = __builtin_elementwise_max(sv[6], sv[7]);
          v2f m4 = __builtin_elementwise_max(sv[8], sv[9]);
          v2f m5 = __builtin_elementwise_max(sv[10], sv[11]);
          v2f m6 = __builtin_elementwise_max(sv[12], sv[13]);
          v2f m7 = __builtin_elementwise_max(sv[14], sv[15]);
          m0 = __builtin_elementwise_max(m0, m1);
          m2 = __builtin_elementwise_max(m2, m3);
          m4 = __builtin_elementwise_max(m4, m5);
          m6 = __builtin_elementwise_max(m6, m7);
          m0 = __builtin_elementwise_max(m0, m2);
          m4 = __builtin_elementwise_max(m4, m6);
          m = __builtin_elementwise_max(m0, m4);
        }
        {
          v2f o;
          o.x = dpp_f<0xB1>(m.x); o.y = dpp_f<0xB1>(m.y);
          m = __builtin_elementwise_max(m, o);
          o.x = dpp_f<0x4E>(m.x); o.y = dpp_f<0x4E>(m.y);
          m = __builtin_elementwise_max(m, o);
          o.x = dpp_f<0x141>(m.x); o.y = dpp_f<0x141>(m.y);
          m = __builtin_elementwise_max(m, o);
        }
        int ai0 = 0xFFFF, ai1 = 0xFFFF;
#pragma unroll
        for (int i = 15; i >= 0; --i) {
          ai0 = (sv[i].x == m.x) ? (i0 + i) : ai0;
          ai1 = (sv[i].y == m.y) ? (i0 + i) : ai1;
        }
        int aip = ai0 | (ai1 << 16);
        aip = pkminu16(aip, dpp_i<0xB1>(aip));
        aip = pkminu16(aip, dpp_i<0x4E>(aip));
        aip = pkminu16(aip, dpp_i<0x141>(aip));

        v2f em2 = emC[s];
        if (rg == 0)
          *(v2f*)(av[t & 1] + AIDX(j0)) = m + em2;
        unsigned int pk = ((unsigned int)aip & 0xFFu) |
                          (((unsigned int)aip >> 8) & 0xFF00u);
        unsigned int sh = pk << ((s & 1) * 16);
        if (s < 2) w0 |= sh; else w1 |= sh;
        BARRIER_LGKM();
      }
      pw0 = w0; pw1 = w1; pend_c = (tc - 1) >> 2;
#pragma unroll
      for (int s = 0; s < 4; ++s) emC[s] = emN[s];
    }
    if (pend_c >= 0 && rg == 1) {
      *(uint2*)(bp + (((b << 7) + pend_c) << 9) + (cg << 3)) =
          make_uint2(pw0, pw1);
    }

    const float* avf = av[(L - 1) & 1];
    {
      float v = (tid < KK) ? avf[AIDX(tid)] : -3.4e38f;
      int idx = (tid < KK) ? tid : KK;
#pragma unroll
      for (int mm = 1; mm < 64; mm <<= 1) {
        float ov = __shfl_xor(v, mm);
        int oi = __shfl_xor(idx, mm);
        if (ov > v || (ov == v && oi < idx)) { v = ov; idx = oi; }
      }
      if ((tid & 63) == 0) { rv[tid >> 6] = v; ri[tid >> 6] = idx; }
    }
    __syncthreads();
    if (tid == 0) {
      float bv = rv[0]; int bi = ri[0];
#pragma unroll
      for (int w = 1; w < 8; ++w)
        if (rv[w] > bv || (rv[w] == bv && ri[w] < bi)) { bv = rv[w]; bi = ri[w]; }
      last_s = bi;
    }
    __syncthreads();
    const int last = last_s;
    if (tid >= L - 1 && tid < TT) tags[tid] = (unsigned char)last;
    __syncthreads();

    if (tid < 64 && L >= 2) {
      const uint2* bpv = (const uint2*)bp;
      int tag = last;
      int cTop = (L - 2) >> 2;
      uint2 q = bpv[(((b << 7) + cTop) << 6) + tid];
      for (int c = cTop; c >= 0; --c) {
        uint2 qn;
        if (c > 0) qn = bpv[(((b << 7) + (c - 1)) << 6) + tid];
        int sHi = (L - 2) - 4 * c; if (sHi > 3) sHi = 3;
#pragma unroll
        for (int s = 3; s >= 0; --s) {
          if (s <= sHi) {
            int word = (s < 2) ? (int)q.x : (int)q.y;
            unsigned int w = (unsigned int)__shfl(word, tag >> 1);
            tag = (int)((w >> ((((s & 1) << 1) | (tag & 1)) << 3)) & 255u);
            if (tid == 0) tags[4 * c + s] = (unsigned char)tag;
          }
        }
        q = qn;
      }
    }
    __syncthreads();
    pred_out[b * TT + tid] = (float)tags[tid];

  } else {
    const int b = blockIdx.x - BB;
    const int L = seq_lens[b];
    __shared__ __align__(16) float ev[2][144];
    __shared__ __align__(16) float wmax[16];
    __shared__ float rs[8]; __shared__ float rsc[8];

    v2f tw[16];
#pragma unroll
    for (int ii = 0; ii < 16; ++ii) {
      v2f tr = *(const v2f*)&trans[(i0 + ii) * KK + j0];
      tw[ii].x = __expf(tr.x);
      tw[ii].y = __expf(tr.y);
    }
    if (tid < KK) ev[0][AIDX(tid)] = __expf(logits[(b * TT) * KK + tid]);
    if (tid < 16) wmax[tid] = 1.0f;

    v2f emC[4], emN[4];
#pragma unroll
    for (int s = 0; s < 4; ++s) {
      int t2 = 1 + s; if (t2 > L - 1) t2 = (L > 1) ? (L - 1) : 0;
      emC[s] = *(const v2f*)&logits[(b * TT + t2) * KK + j0];
    }
    __syncthreads();

    float Cln = 0.0f;
    for (int tc = 1; tc < L; tc += 4) {
#pragma unroll
      for (int s = 0; s < 4; ++s) {
        int t2 = tc + 4 + s; if (t2 > L - 1) t2 = L - 1;
        emN[s] = *(const v2f*)&logits[(b * TT + t2) * KK + j0];
      }
      float r;
      {
        float4 w0 = *(const float4*)&wmax[0];
        float4 w1 = *(const float4*)&wmax[4];
        float4 w2 = *(const float4*)&wmax[8];
        float4 w3 = *(const float4*)&wmax[12];
        float U = fmaxf(fmaxf(fmaxf(w0.x, w0.y), fmaxf(w0.z, w0.w)),
                        fmaxf(fmaxf(w1.x, w1.y), fmaxf(w1.z, w1.w)));
        U = fmaxf(U, fmaxf(fmaxf(fmaxf(w2.x, w2.y), fmaxf(w2.z, w2.w)),
                           fmaxf(fmaxf(w3.x, w3.y), fmaxf(w3.z, w3.w))));
        int ex = (__float_as_int(U) >> 23) & 255;
        r = __int_as_float((254 - ex) << 23);
        Cln += (float)(ex - 127) * 0.6931471805599453f;
      }
#pragma unroll
      for (int s = 0; s < 4; ++s) {
        const int t = tc + s;
        if (t >= L) break;
        const float4* evr = (const float4*)(ev[(t & 1) ^ 1] + AIDX(i0));
        v2f S2 = {0.0f, 0.0f};
#pragma unroll
        for (int q = 0; q < 4; ++q) {
          float4 e4 = evr[q];
#pragma unroll
          for (int c = 0; c < 4; ++c) {
            float e = (c == 0) ? e4.x : (c == 1) ? e4.y : (c == 2) ? e4.z : e4.w;
            S2 += (v2f){e, e} * tw[q * 4 + c];
          }
        }
        {
          v2f o;
          o.x = dpp_f<0xB1>(S2.x); o.y = dpp_f<0xB1>(S2.y); S2 += o;
          o.x = dpp_f<0x4E>(S2.x); o.y = dpp_f<0x4E>(S2.y); S2 += o;
          o.x = dpp_f<0x141>(S2.x); o.y = dpp_f<0x141>(S2.y); S2 += o;
        }
        v2f em2 = emC[s];
        float evn0 = S2.x * __expf(em2.x);
        float evn1 = S2.y * __expf(em2.y);
        if (s == 0) { evn0 *= r; evn1 *= r; }
        if (rg == 0)
          *(v2f*)(ev[t & 1] + AIDX(j0)) = (v2f){evn0, evn1};
        if (s == 3) {
          float wm = fmaxf(evn0, evn1);
          wm = fmaxf(wm, dpp_f<0x140>(wm));
          wm = fmaxf(wm, swz16_f(wm));
          if ((tid & 31) == 0) wmax[tid >> 5] = wm;
        }
        BARRIER_LGKM();
      }
#pragma unroll
      for (int s = 0; s < 4; ++s) emC[s] = emN[s];
    }

    const float* evf = ev[(L - 1) & 1];
    {
      float ssum = (tid < KK) ? evf[AIDX(tid)] : 0.0f;
#pragma unroll
      for (int mm = 1; mm < 64; mm <<= 1) ssum += __shfl_xor(ssum, mm);
      if ((tid & 63) == 0) rs[tid >> 6] = ssum;
    }
    float sc = 0.0f;
    for (int tt2 = tid; tt2 < L; tt2 += 512) {
      int lab = labels[b * TT + tt2];
      sc += logits[(b * TT + tt2) * KK + lab];
      if (tt2 >= 1) sc += trans[labels[b * TT + tt2 - 1] * KK + lab];
    }
#pragma unroll
    for (int mm = 1; mm < 64; mm <<= 1) sc += __shfl_xor(sc, mm);
    if ((tid & 63) == 0) rsc[tid >> 6] = sc;
    __syncthreads();
    if (tid == 0) {
      float es = rs[0]; float scf = rsc[0];
#pragma unroll
      for (int w = 1; w < 8; ++w) { es += rs[w]; scf += rsc[w]; }
      negll[b] = (Cln + logf(es)) - scf;
    }
  }
}

__global__ void crf_loss_reduce(const float* __restrict__ negll, float* __restrict__ out) {
  int tid = threadIdx.x;
  float v = negll[tid];
#pragma unroll
  for (int m = 1; m < 64; m <<= 1) v += __shfl_xor(v, m);
  __shared__ float p[4];
  if ((tid & 63) == 0) p[tid >> 6] = v;
  __syncthreads();
  if (tid == 0) out[0] = p[0] + p[1] + p[2] + p[3];
}

extern "C" void kernel_launch(void* const* d_in, const int* in_sizes, int n_in,
                              void* d_out, int out_size, void* d_ws, size_t ws_size,
                              hipStream_t stream) {
  const float* logits   = (const float*)d_in[0];
  const int*   labels   = (const int*)d_in[1];
  const int*   seq_lens = (const int*)d_in[2];
  const float* trans    = (const float*)d_in[3];
  float* out = (float*)d_out;

  float* negll = (float*)d_ws;                          // [0, 1KB): 256 floats
  const size_t ALPHA_OFF = 4096;
  const size_t NEED = ALPHA_OFF + (size_t)BB * TT * KK * 4;   // ~67.1 MB

  if (ws_size >= NEED) {
    int*   lastIdx = (int*)((char*)d_ws + 1024);        // [1KB, 2KB)
    float* alpha   = (float*)((char*)d_ws + ALPHA_OFF); // [4KB, 4KB+67.1MB)
    crf_fwd<<<2 * BB, 512, 0, stream>>>(logits, labels, seq_lens, trans,
                                        negll, lastIdx, alpha);
    crf_backtrack<<<BB, 64, 0, stream>>>(alpha, seq_lens, lastIdx, trans,
                                         out + 1);
  } else {
    unsigned char* bp = (unsigned char*)d_ws + 1024;    // 16.8 MB
    crf_main_fb<<<2 * BB, 512, 0, stream>>>(logits, labels, seq_lens, trans,
                                            out + 1, negll, bp);
  }
  crf_loss_reduce<<<1, 256, 0, stream>>>(negll, out);
}

// Round 5
// 573.916 us; speedup vs baseline: 1.1687x; 1.1687x over previous
//
#include <hip/hip_runtime.h>
#include <math.h>

#define BB 256
#define TT 512
#define KK 128
#define AIDX(i) ((i) + (((i) >> 5) << 2))

typedef float v2f __attribute__((ext_vector_type(2)));
typedef unsigned short u16v2 __attribute__((ext_vector_type(2)));

template<int CTRL>
__device__ __forceinline__ int dpp_i(int x) {
  return __builtin_amdgcn_update_dpp(x, x, CTRL, 0xF, 0xF, true);
}
template<int CTRL>
__device__ __forceinline__ float dpp_f(float x) {
  return __int_as_float(dpp_i<CTRL>(__float_as_int(x)));
}
__device__ __forceinline__ float swz16_f(float x) {
  return __int_as_float(__builtin_amdgcn_ds_swizzle(__float_as_int(x), 0x401F));
}
__device__ __forceinline__ int pkminu16(int a, int b) {
  u16v2 av = *(u16v2*)&a, bv = *(u16v2*)&b;
  u16v2 r = __builtin_elementwise_min(av, bv);
  return *(int*)&r;
}
// barrier that drains LDS only (not vmcnt) — keeps prefetch loads in flight
#define BARRIER_LGKM() asm volatile("s_waitcnt lgkmcnt(0)\ns_barrier" ::: "memory")

// ============================================================================
// Phase 1: viterbi WITHOUT argmax scan — streams the pre-emission max vector
// m_t (NOT alpha) to global; + forward (log-norm) unchanged.
// ============================================================================
__global__ __launch_bounds__(512, 4) void crf_fwd(
    const float* __restrict__ logits,     // [B,T,K]
    const int* __restrict__ labels,       // [B,T]
    const int* __restrict__ seq_lens,     // [B]
    const float* __restrict__ trans,      // [K,K]
    float* __restrict__ negll,            // [B] in ws
    int* __restrict__ lastIdx,            // [B] in ws
    float* __restrict__ mOut)             // [B][T][K] in ws (t>=1 valid)
{
  const int tid = threadIdx.x;
  const int cg = tid >> 3, rg = tid & 7;
  const int j0 = cg * 2, i0 = rg * 16;

  if (blockIdx.x < BB) {
    // ================= VITERBI (scan-free, m streamed) =================
    const int b = blockIdx.x;
    const int L = seq_lens[b];
    __shared__ __align__(16) float av[2][144];
    __shared__ float rv[8]; __shared__ int ri[8];

    v2f tv[16];
#pragma unroll
    for (int ii = 0; ii < 16; ++ii)
      tv[ii] = *(const v2f*)&trans[(i0 + ii) * KK + j0];

    if (tid < KK) av[0][AIDX(tid)] = logits[(b * TT) * KK + tid];

    v2f emC[4], emN[4];
#pragma unroll
    for (int s = 0; s < 4; ++s) {
      int t2 = 1 + s; if (t2 > L - 1) t2 = (L > 1) ? (L - 1) : 0;
      emC[s] = *(const v2f*)&logits[(b * TT + t2) * KK + j0];
    }
    __syncthreads();

    for (int tc = 1; tc < L; tc += 4) {
#pragma unroll
      for (int s = 0; s < 4; ++s) {
        int t2 = tc + 4 + s; if (t2 > L - 1) t2 = L - 1;
        emN[s] = *(const v2f*)&logits[(b * TT + t2) * KK + j0];
      }
#pragma unroll
      for (int s = 0; s < 4; ++s) {
        const int t = tc + s;
        if (t >= L) break;
        const float4* avr = (const float4*)(av[(t & 1) ^ 1] + AIDX(i0));
        v2f sv[16];
#pragma unroll
        for (int q = 0; q < 4; ++q) {
          float4 a4 = avr[q];
#pragma unroll
          for (int c = 0; c < 4; ++c) {
            float a = (c == 0) ? a4.x : (c == 1) ? a4.y : (c == 2) ? a4.z : a4.w;
            sv[q * 4 + c] = (v2f){a, a} + tv[q * 4 + c];   // exact IEEE adds
          }
        }
        // in-thread max tree (exact; max is order-insensitive, returns operand bits)
        v2f m;
        {
          v2f m0 = __builtin_elementwise_max(sv[0], sv[1]);
          v2f m1 = __builtin_elementwise_max(sv[2], sv[3]);
          v2f m2 = __builtin_elementwise_max(sv[4], sv[5]);
          v2f m3 = __builtin_elementwise_max(sv[6], sv[7]);
          v2f m4 = __builtin_elementwise_max(sv[8], sv[9]);
          v2f m5 = __builtin_elementwise_max(sv[10], sv[11]);
          v2f m6 = __builtin_elementwise_max(sv[12], sv[13]);
          v2f m7 = __builtin_elementwise_max(sv[14], sv[15]);
          m0 = __builtin_elementwise_max(m0, m1);
          m2 = __builtin_elementwise_max(m2, m3);
          m4 = __builtin_elementwise_max(m4, m5);
          m6 = __builtin_elementwise_max(m6, m7);
          m0 = __builtin_elementwise_max(m0, m2);
          m4 = __builtin_elementwise_max(m4, m6);
          m = __builtin_elementwise_max(m0, m4);
        }
        // cross-row-group max: xor1, xor2, xor4 — all DPP
        {
          v2f o;
          o.x = dpp_f<0xB1>(m.x); o.y = dpp_f<0xB1>(m.y);
          m = __builtin_elementwise_max(m, o);
          o.x = dpp_f<0x4E>(m.x); o.y = dpp_f<0x4E>(m.y);
          m = __builtin_elementwise_max(m, o);
          o.x = dpp_f<0x141>(m.x); o.y = dpp_f<0x141>(m.y);
          m = __builtin_elementwise_max(m, o);
        }
        v2f nav = m + emC[s];
        if (rg == 0) {
          *(v2f*)(av[t & 1] + AIDX(j0)) = nav;
          *(v2f*)&mOut[(b * TT + t) * KK + j0] = m;   // stream m_t
        }
        BARRIER_LGKM();
      }
#pragma unroll
      for (int s = 0; s < 4; ++s) emC[s] = emN[s];
    }

    // final argmax across K → lastIdx
    const float* avf = av[(L - 1) & 1];
    {
      float v = (tid < KK) ? avf[AIDX(tid)] : -3.4e38f;
      int idx = (tid < KK) ? tid : KK;
#pragma unroll
      for (int mm = 1; mm < 64; mm <<= 1) {
        float ov = __shfl_xor(v, mm);
        int oi = __shfl_xor(idx, mm);
        if (ov > v || (ov == v && oi < idx)) { v = ov; idx = oi; }
      }
      if ((tid & 63) == 0) { rv[tid >> 6] = v; ri[tid >> 6] = idx; }
    }
    __syncthreads();
    if (tid == 0) {
      float bv = rv[0]; int bi = ri[0];
#pragma unroll
      for (int w = 1; w < 8; ++w)
        if (rv[w] > bv || (rv[w] == bv && ri[w] < bi)) { bv = rv[w]; bi = ri[w]; }
      lastIdx[b] = bi;
    }

  } else {
    // ================= FORWARD (log-norm) — unchanged from 438us baseline ===
    const int b = blockIdx.x - BB;
    const int L = seq_lens[b];
    __shared__ __align__(16) float ev[2][144];
    __shared__ __align__(16) float wmax[16];
    __shared__ float rs[8]; __shared__ float rsc[8];

    v2f tw[16];
#pragma unroll
    for (int ii = 0; ii < 16; ++ii) {
      v2f tr = *(const v2f*)&trans[(i0 + ii) * KK + j0];
      tw[ii].x = __expf(tr.x);
      tw[ii].y = __expf(tr.y);
    }
    if (tid < KK) ev[0][AIDX(tid)] = __expf(logits[(b * TT) * KK + tid]);
    if (tid < 16) wmax[tid] = 1.0f;

    v2f emC[4], emN[4];
#pragma unroll
    for (int s = 0; s < 4; ++s) {
      int t2 = 1 + s; if (t2 > L - 1) t2 = (L > 1) ? (L - 1) : 0;
      emC[s] = *(const v2f*)&logits[(b * TT + t2) * KK + j0];
    }
    __syncthreads();

    float Cln = 0.0f;
    for (int tc = 1; tc < L; tc += 4) {
#pragma unroll
      for (int s = 0; s < 4; ++s) {
        int t2 = tc + 4 + s; if (t2 > L - 1) t2 = L - 1;
        emN[s] = *(const v2f*)&logits[(b * TT + t2) * KK + j0];
      }
      // renorm factor (exact pow2), once per 4-step chunk
      float r;
      {
        float4 w0 = *(const float4*)&wmax[0];
        float4 w1 = *(const float4*)&wmax[4];
        float4 w2 = *(const float4*)&wmax[8];
        float4 w3 = *(const float4*)&wmax[12];
        float U = fmaxf(fmaxf(fmaxf(w0.x, w0.y), fmaxf(w0.z, w0.w)),
                        fmaxf(fmaxf(w1.x, w1.y), fmaxf(w1.z, w1.w)));
        U = fmaxf(U, fmaxf(fmaxf(fmaxf(w2.x, w2.y), fmaxf(w2.z, w2.w)),
                           fmaxf(fmaxf(w3.x, w3.y), fmaxf(w3.z, w3.w))));
        int ex = (__float_as_int(U) >> 23) & 255;
        r = __int_as_float((254 - ex) << 23);
        Cln += (float)(ex - 127) * 0.6931471805599453f;
      }
#pragma unroll
      for (int s = 0; s < 4; ++s) {
        const int t = tc + s;
        if (t >= L) break;
        const float4* evr = (const float4*)(ev[(t & 1) ^ 1] + AIDX(i0));
        v2f S2 = {0.0f, 0.0f};
#pragma unroll
        for (int q = 0; q < 4; ++q) {
          float4 e4 = evr[q];
#pragma unroll
          for (int c = 0; c < 4; ++c) {
            float e = (c == 0) ? e4.x : (c == 1) ? e4.y : (c == 2) ? e4.z : e4.w;
            S2 += (v2f){e, e} * tw[q * 4 + c];   // pk_fma
          }
        }
        {
          v2f o;
          o.x = dpp_f<0xB1>(S2.x); o.y = dpp_f<0xB1>(S2.y); S2 += o;
          o.x = dpp_f<0x4E>(S2.x); o.y = dpp_f<0x4E>(S2.y); S2 += o;
          o.x = dpp_f<0x141>(S2.x); o.y = dpp_f<0x141>(S2.y); S2 += o;
        }
        v2f em2 = emC[s];
        float evn0 = S2.x * __expf(em2.x);
        float evn1 = S2.y * __expf(em2.y);
        if (s == 0) { evn0 *= r; evn1 *= r; }
        if (rg == 0)
          *(v2f*)(ev[t & 1] + AIDX(j0)) = (v2f){evn0, evn1};
        if (s == 3) {
          float wm = fmaxf(evn0, evn1);
          wm = fmaxf(wm, dpp_f<0x140>(wm));   // xor8 (values 8-uniform)
          wm = fmaxf(wm, swz16_f(wm));        // xor16
          if ((tid & 31) == 0) wmax[tid >> 5] = wm;
        }
        BARRIER_LGKM();
      }
#pragma unroll
      for (int s = 0; s < 4; ++s) emC[s] = emN[s];
    }

    const float* evf = ev[(L - 1) & 1];
    {
      float ssum = (tid < KK) ? evf[AIDX(tid)] : 0.0f;
#pragma unroll
      for (int mm = 1; mm < 64; mm <<= 1) ssum += __shfl_xor(ssum, mm);
      if ((tid & 63) == 0) rs[tid >> 6] = ssum;
    }
    float sc = 0.0f;
    for (int tt2 = tid; tt2 < L; tt2 += 512) {
      int lab = labels[b * TT + tt2];
      sc += logits[(b * TT + tt2) * KK + lab];
      if (tt2 >= 1) sc += trans[labels[b * TT + tt2 - 1] * KK + lab];
    }
#pragma unroll
    for (int mm = 1; mm < 64; mm <<= 1) sc += __shfl_xor(sc, mm);
    if ((tid & 63) == 0) rsc[tid >> 6] = sc;
    __syncthreads();
    if (tid == 0) {
      float es = rs[0]; float scf = rsc[0];
#pragma unroll
      for (int w = 1; w < 8; ++w) { es += rs[w]; scf += rsc[w]; }
      negll[b] = (Cln + logf(es)) - scf;
    }
  }
}

// ============================================================================
// Phase 2: backtrack via EQUALITY MATCH against streamed m — no cross-lane
// max reduce. Per step: tag -> {readlane m_t[tag] || ds_read tT[tag] row}
// -> 2 add + 2 cmp -> ballot -> s_ff1 -> readlane. ~170 cyc/step.
// alpha_{t-1}[i] = m_{t-1}[i] + logits[t-1][i] (bit-exact phase-1 add);
// alpha_0 = logits[0]. First set lane = first index (jnp.argmax tie rule).
// ============================================================================
__global__ __launch_bounds__(64, 1) void crf_backtrack(
    const float* __restrict__ mvec,       // [B][T][K] in ws (t>=1 valid)
    const float* __restrict__ logits,     // [B,T,K]
    const int* __restrict__ seq_lens,     // [B]
    const int* __restrict__ lastIdx,      // [B] in ws
    const float* __restrict__ trans,      // [K,K]
    float* __restrict__ pred_out)         // [B,T] as float
{
  const int b = blockIdx.x, l = threadIdx.x;
  const int L = seq_lens[b];
  __shared__ float tT[KK][KK + 2];        // transposed trans; row stride 520 B
  __shared__ float tagsf[TT];

  // build transpose (one-time)
  for (int i = 0; i < KK; ++i) {
    v2f r = *(const v2f*)&trans[i * KK + 2 * l];
    tT[2 * l][i] = r.x;
    tT[2 * l + 1][i] = r.y;
  }
  const int last = lastIdx[b];
  for (int t = l; t < TT; t += 64) tagsf[t] = (float)last;   // t >= L-1 keeps last
  __syncthreads();

  if (L >= 2) {
    const float* mb = mvec  + (size_t)(b * TT) * KK + 2 * l;
    const float* gb = logits + (size_t)(b * TT) * KK + 2 * l;
    int tag = last;
    v2f zero = {0.0f, 0.0f};
    v2f mvC = *(const v2f*)&mb[(L - 1) * KK];   // m at time t = L-1

    // 4-deep prefetch pipeline; stage k holds data for time (t-1-k)
    v2f lg0 = zero, mv0 = zero, lg1 = zero, mv1 = zero;
    v2f lg2 = zero, mv2 = zero, lg3 = zero, mv3 = zero;
    {
      int s0 = L - 2, s1 = L - 3, s2 = L - 4, s3 = L - 5;
      if (s0 >= 0) { lg0 = *(const v2f*)&gb[s0 * KK]; if (s0 >= 1) mv0 = *(const v2f*)&mb[s0 * KK]; }
      if (s1 >= 0) { lg1 = *(const v2f*)&gb[s1 * KK]; if (s1 >= 1) mv1 = *(const v2f*)&mb[s1 * KK]; }
      if (s2 >= 0) { lg2 = *(const v2f*)&gb[s2 * KK]; if (s2 >= 1) mv2 = *(const v2f*)&mb[s2 * KK]; }
      if (s3 >= 0) { lg3 = *(const v2f*)&gb[s3 * KK]; if (s3 >= 1) mv3 = *(const v2f*)&mb[s3 * KK]; }
    }

    for (int t = L - 1; t >= 1; --t) {
      const int tp = t - 1;
      // alpha_{t-1} (tag-independent, ready early)
      v2f aP = (tp >= 1) ? (mv0 + lg0) : lg0;
      // target = m_t[tag] via readlane (parallel with the LDS row read)
      int lanem = tag >> 1;
      int txi = __builtin_amdgcn_readlane(__float_as_int(mvC.x), lanem);
      int tyi = __builtin_amdgcn_readlane(__float_as_int(mvC.y), lanem);
      float target = __int_as_float((tag & 1) ? tyi : txi);
      // trans column for tag (row of tT) — the only tag-dependent memory op
      v2f col = *(const v2f*)&tT[tag][2 * l];
      v2f sv = aP + col;                           // bit-exact phase-1 adds
      bool h0 = (sv.x == target), h1 = (sv.y == target);
      unsigned long long mask = __ballot(h0 || h1);
      int first = __ffsll(mask) - 1;               // lowest matching lane
      int cand = h0 ? (2 * l) : (2 * l + 1);       // first index within lane
      tag = __builtin_amdgcn_readlane(cand, first);
      if (l == 0) tagsf[tp] = (float)tag;
      // shift pipeline; m of time tp becomes current
      mvC = mv0;
      lg0 = lg1; mv0 = mv1;
      lg1 = lg2; mv1 = mv2;
      lg2 = lg3; mv2 = mv3;
      int sN = t - 5;                              // next iter's stage-3 time
      if (sN >= 0) {
        lg3 = *(const v2f*)&gb[sN * KK];
        mv3 = (sN >= 1) ? *(const v2f*)&mb[sN * KK] : zero;
      } else { lg3 = zero; mv3 = zero; }
    }
  }
  __syncthreads();
#pragma unroll
  for (int k = 0; k < 8; ++k)
    pred_out[b * TT + l * 8 + k] = tagsf[l * 8 + k];
}

// ============================================================================
// FALLBACK: verbatim 438us two-block kernel (bp in ws), used if ws too small.
// ============================================================================
__global__ __launch_bounds__(512, 4) void crf_main_fb(
    const float* __restrict__ logits,
    const int* __restrict__ labels,
    const int* __restrict__ seq_lens,
    const float* __restrict__ trans,
    float* __restrict__ pred_out,
    float* __restrict__ negll,
    unsigned char* __restrict__ bp)
{
  const int tid = threadIdx.x;
  const int cg = tid >> 3, rg = tid & 7;
  const int j0 = cg * 2, i0 = rg * 16;

  if (blockIdx.x < BB) {
    const int b = blockIdx.x;
    const int L = seq_lens[b];
    __shared__ __align__(16) float av[2][144];
    __shared__ unsigned char tags[TT];
    __shared__ float rv[8]; __shared__ int ri[8];
    __shared__ int last_s;

    v2f tv[16];
#pragma unroll
    for (int ii = 0; ii < 16; ++ii)
      tv[ii] = *(const v2f*)&trans[(i0 + ii) * KK + j0];

    if (tid < KK) av[0][AIDX(tid)] = logits[(b * TT) * KK + tid];

    v2f emC[4], emN[4];
#pragma unroll
    for (int s = 0; s < 4; ++s) {
      int t2 = 1 + s; if (t2 > L - 1) t2 = (L > 1) ? (L - 1) : 0;
      emC[s] = *(const v2f*)&logits[(b * TT + t2) * KK + j0];
    }
    __syncthreads();

    unsigned int pw0 = 0, pw1 = 0; int pend_c = -1;

    for (int tc = 1; tc < L; tc += 4) {
#pragma unroll
      for (int s = 0; s < 4; ++s) {
        int t2 = tc + 4 + s; if (t2 > L - 1) t2 = L - 1;
        emN[s] = *(const v2f*)&logits[(b * TT + t2) * KK + j0];
      }
      if (pend_c >= 0 && rg == 1) {
        *(uint2*)(bp + (((b << 7) + pend_c) << 9) + (cg << 3)) =
            make_uint2(pw0, pw1);
      }
      unsigned int w0 = 0, w1 = 0;
#pragma unroll
      for (int s = 0; s < 4; ++s) {
        const int t = tc + s;
        if (t >= L) break;
        const float4* avr = (const float4*)(av[(t & 1) ^ 1] + AIDX(i0));
        v2f sv[16];
#pragma unroll
        for (int q = 0; q < 4; ++q) {
          float4 a4 = avr[q];
#pragma unroll
          for (int c = 0; c < 4; ++c) {
            float a = (c == 0) ? a4.x : (c == 1) ? a4.y : (c == 2) ? a4.z : a4.w;
            sv[q * 4 + c] = (v2f){a, a} + tv[q * 4 + c];
          }
        }
        v2f m;
        {
          v2f m0 = __builtin_elementwise_max(sv[0], sv[1]);
          v2f m1 = __builtin_elementwise_max(sv[2], sv[3]);
          v2f m2 = __builtin_elementwise_max(sv[4], sv[5]);
          v2f m3 = __builtin_elementwise_max(sv[6], sv[7]);
          v2f m4 = __builtin_elementwise_max(sv[8], sv[9]);
          v2f m5 = __builtin_elementwise_max(sv[10], sv[11]);
          v2f m6 = __builtin_elementwise_max(sv[12], sv[13]);
          v2f m7 = __builtin_elementwise_max(sv[14], sv[15]);
          m0 = __builtin_elementwise_max(m0, m1);
          m2 = __builtin_elementwise_max(m2, m3);
          m4 = __builtin_elementwise_max(m4, m5);
          m6 = __builtin_elementwise_max(m6, m7);
          m0 = __builtin_elementwise_max(m0, m2);
          m4 = __builtin_elementwise_max(m4, m6);
          m = __builtin_elementwise_max(m0, m4);
        }
        {
          v2f o;
          o.x = dpp_f<0xB1>(m.x); o.y = dpp_f<0xB1>(m.y);
          m = __builtin_elementwise_max(m, o);
          o.x = dpp_f<0x4E>(m.x); o.y = dpp_f<0x4E>(m.y);
          m = __builtin_elementwise_max(m, o);
          o.x = dpp_f<0x141>(m.x); o.y = dpp_f<0x141>(m.y);
          m = __builtin_elementwise_max(m, o);
        }
        int ai0 = 0xFFFF, ai1 = 0xFFFF;
#pragma unroll
        for (int i = 15; i >= 0; --i) {
          ai0 = (sv[i].x == m.x) ? (i0 + i) : ai0;
          ai1 = (sv[i].y == m.y) ? (i0 + i) : ai1;
        }
        int aip = ai0 | (ai1 << 16);
        aip = pkminu16(aip, dpp_i<0xB1>(aip));
        aip = pkminu16(aip, dpp_i<0x4E>(aip));
        aip = pkminu16(aip, dpp_i<0x141>(aip));

        v2f em2 = emC[s];
        if (rg == 0)
          *(v2f*)(av[t & 1] + AIDX(j0)) = m + em2;
        unsigned int pk = ((unsigned int)aip & 0xFFu) |
                          (((unsigned int)aip >> 8) & 0xFF00u);
        unsigned int sh = pk << ((s & 1) * 16);
        if (s < 2) w0 |= sh; else w1 |= sh;
        BARRIER_LGKM();
      }
      pw0 = w0; pw1 = w1; pend_c = (tc - 1) >> 2;
#pragma unroll
      for (int s = 0; s < 4; ++s) emC[s] = emN[s];
    }
    if (pend_c >= 0 && rg == 1) {
      *(uint2*)(bp + (((b << 7) + pend_c) << 9) + (cg << 3)) =
          make_uint2(pw0, pw1);
    }

    const float* avf = av[(L - 1) & 1];
    {
      float v = (tid < KK) ? avf[AIDX(tid)] : -3.4e38f;
      int idx = (tid < KK) ? tid : KK;
#pragma unroll
      for (int mm = 1; mm < 64; mm <<= 1) {
        float ov = __shfl_xor(v, mm);
        int oi = __shfl_xor(idx, mm);
        if (ov > v || (ov == v && oi < idx)) { v = ov; idx = oi; }
      }
      if ((tid & 63) == 0) { rv[tid >> 6] = v; ri[tid >> 6] = idx; }
    }
    __syncthreads();
    if (tid == 0) {
      float bv = rv[0]; int bi = ri[0];
#pragma unroll
      for (int w = 1; w < 8; ++w)
        if (rv[w] > bv || (rv[w] == bv && ri[w] < bi)) { bv = rv[w]; bi = ri[w]; }
      last_s = bi;
    }
    __syncthreads();
    const int last = last_s;
    if (tid >= L - 1 && tid < TT) tags[tid] = (unsigned char)last;
    __syncthreads();

    if (tid < 64 && L >= 2) {
      const uint2* bpv = (const uint2*)bp;
      int tag = last;
      int cTop = (L - 2) >> 2;
      uint2 q = bpv[(((b << 7) + cTop) << 6) + tid];
      for (int c = cTop; c >= 0; --c) {
        uint2 qn;
        if (c > 0) qn = bpv[(((b << 7) + (c - 1)) << 6) + tid];
        int sHi = (L - 2) - 4 * c; if (sHi > 3) sHi = 3;
#pragma unroll
        for (int s = 3; s >= 0; --s) {
          if (s <= sHi) {
            int word = (s < 2) ? (int)q.x : (int)q.y;
            unsigned int w = (unsigned int)__shfl(word, tag >> 1);
            tag = (int)((w >> ((((s & 1) << 1) | (tag & 1)) << 3)) & 255u);
            if (tid == 0) tags[4 * c + s] = (unsigned char)tag;
          }
        }
        q = qn;
      }
    }
    __syncthreads();
    pred_out[b * TT + tid] = (float)tags[tid];

  } else {
    const int b = blockIdx.x - BB;
    const int L = seq_lens[b];
    __shared__ __align__(16) float ev[2][144];
    __shared__ __align__(16) float wmax[16];
    __shared__ float rs[8]; __shared__ float rsc[8];

    v2f tw[16];
#pragma unroll
    for (int ii = 0; ii < 16; ++ii) {
      v2f tr = *(const v2f*)&trans[(i0 + ii) * KK + j0];
      tw[ii].x = __expf(tr.x);
      tw[ii].y = __expf(tr.y);
    }
    if (tid < KK) ev[0][AIDX(tid)] = __expf(logits[(b * TT) * KK + tid]);
    if (tid < 16) wmax[tid] = 1.0f;

    v2f emC[4], emN[4];
#pragma unroll
    for (int s = 0; s < 4; ++s) {
      int t2 = 1 + s; if (t2 > L - 1) t2 = (L > 1) ? (L - 1) : 0;
      emC[s] = *(const v2f*)&logits[(b * TT + t2) * KK + j0];
    }
    __syncthreads();

    float Cln = 0.0f;
    for (int tc = 1; tc < L; tc += 4) {
#pragma unroll
      for (int s = 0; s < 4; ++s) {
        int t2 = tc + 4 + s; if (t2 > L - 1) t2 = L - 1;
        emN[s] = *(const v2f*)&logits[(b * TT + t2) * KK + j0];
      }
      float r;
      {
        float4 w0 = *(const float4*)&wmax[0];
        float4 w1 = *(const float4*)&wmax[4];
        float4 w2 = *(const float4*)&wmax[8];
        float4 w3 = *(const float4*)&wmax[12];
        float U = fmaxf(fmaxf(fmaxf(w0.x, w0.y), fmaxf(w0.z, w0.w)),
                        fmaxf(fmaxf(w1.x, w1.y), fmaxf(w1.z, w1.w)));
        U = fmaxf(U, fmaxf(fmaxf(fmaxf(w2.x, w2.y), fmaxf(w2.z, w2.w)),
                           fmaxf(fmaxf(w3.x, w3.y), fmaxf(w3.z, w3.w))));
        int ex = (__float_as_int(U) >> 23) & 255;
        r = __int_as_float((254 - ex) << 23);
        Cln += (float)(ex - 127) * 0.6931471805599453f;
      }
#pragma unroll
      for (int s = 0; s < 4; ++s) {
        const int t = tc + s;
        if (t >= L) break;
        const float4* evr = (const float4*)(ev[(t & 1) ^ 1] + AIDX(i0));
        v2f S2 = {0.0f, 0.0f};
#pragma unroll
        for (int q = 0; q < 4; ++q) {
          float4 e4 = evr[q];
#pragma unroll
          for (int c = 0; c < 4; ++c) {
            float e = (c == 0) ? e4.x : (c == 1) ? e4.y : (c == 2) ? e4.z : e4.w;
            S2 += (v2f){e, e} * tw[q * 4 + c];
          }
        }
        {
          v2f o;
          o.x = dpp_f<0xB1>(S2.x); o.y = dpp_f<0xB1>(S2.y); S2 += o;
          o.x = dpp_f<0x4E>(S2.x); o.y = dpp_f<0x4E>(S2.y); S2 += o;
          o.x = dpp_f<0x141>(S2.x); o.y = dpp_f<0x141>(S2.y); S2 += o;
        }
        v2f em2 = emC[s];
        float evn0 = S2.x * __expf(em2.x);
        float evn1 = S2.y * __expf(em2.y);
        if (s == 0) { evn0 *= r; evn1 *= r; }
        if (rg == 0)
          *(v2f*)(ev[t & 1] + AIDX(j0)) = (v2f){evn0, evn1};
        if (s == 3) {
          float wm = fmaxf(evn0, evn1);
          wm = fmaxf(wm, dpp_f<0x140>(wm));
          wm = fmaxf(wm, swz16_f(wm));
          if ((tid & 31) == 0) wmax[tid >> 5] = wm;
        }
        BARRIER_LGKM();
      }
#pragma unroll
      for (int s = 0; s < 4; ++s) emC[s] = emN[s];
    }

    const float* evf = ev[(L - 1) & 1];
    {
      float ssum = (tid < KK) ? evf[AIDX(tid)] : 0.0f;
#pragma unroll
      for (int mm = 1; mm < 64; mm <<= 1) ssum += __shfl_xor(ssum, mm);
      if ((tid & 63) == 0) rs[tid >> 6] = ssum;
    }
    float sc = 0.0f;
    for (int tt2 = tid; tt2 < L; tt2 += 512) {
      int lab = labels[b * TT + tt2];
      sc += logits[(b * TT + tt2) * KK + lab];
      if (tt2 >= 1) sc += trans[labels[b * TT + tt2 - 1] * KK + lab];
    }
#pragma unroll
    for (int mm = 1; mm < 64; mm <<= 1) sc += __shfl_xor(sc, mm);
    if ((tid & 63) == 0) rsc[tid >> 6] = sc;
    __syncthreads();
    if (tid == 0) {
      float es = rs[0]; float scf = rsc[0];
#pragma unroll
      for (int w = 1; w < 8; ++w) { es += rs[w]; scf += rsc[w]; }
      negll[b] = (Cln + logf(es)) - scf;
    }
  }
}

__global__ void crf_loss_reduce(const float* __restrict__ negll, float* __restrict__ out) {
  int tid = threadIdx.x;
  float v = negll[tid];
#pragma unroll
  for (int m = 1; m < 64; m <<= 1) v += __shfl_xor(v, m);
  __shared__ float p[4];
  if ((tid & 63) == 0) p[tid >> 6] = v;
  __syncthreads();
  if (tid == 0) out[0] = p[0] + p[1] + p[2] + p[3];
}

extern "C" void kernel_launch(void* const* d_in, const int* in_sizes, int n_in,
                              void* d_out, int out_size, void* d_ws, size_t ws_size,
                              hipStream_t stream) {
  const float* logits   = (const float*)d_in[0];
  const int*   labels   = (const int*)d_in[1];
  const int*   seq_lens = (const int*)d_in[2];
  const float* trans    = (const float*)d_in[3];
  float* out = (float*)d_out;

  float* negll = (float*)d_ws;                          // [0, 1KB): 256 floats
  const size_t M_OFF = 4096;
  const size_t NEED = M_OFF + (size_t)BB * TT * KK * 4;   // ~67.1 MB

  if (ws_size >= NEED) {
    int*   lastIdx = (int*)((char*)d_ws + 1024);        // [1KB, 2KB)
    float* mOut    = (float*)((char*)d_ws + M_OFF);     // [4KB, 4KB+67.1MB)
    crf_fwd<<<2 * BB, 512, 0, stream>>>(logits, labels, seq_lens, trans,
                                        negll, lastIdx, mOut);
    crf_backtrack<<<BB, 64, 0, stream>>>(mOut, logits, seq_lens, lastIdx,
                                         trans, out + 1);
  } else {
    unsigned char* bp = (unsigned char*)d_ws + 1024;    // 16.8 MB
    crf_main_fb<<<2 * BB, 512, 0, stream>>>(logits, labels, seq_lens, trans,
                                            out + 1, negll, bp);
  }
  crf_loss_reduce<<<1, 256, 0, stream>>>(negll, out);
}

// Round 6
// 435.278 us; speedup vs baseline: 1.5410x; 1.3185x over previous
//
#include <hip/hip_runtime.h>
#include <math.h>

#define BB 256
#define TT 512
#define KK 128
#define AIDX(i) ((i) + (((i) >> 5) << 2))

typedef float v2f __attribute__((ext_vector_type(2)));
typedef unsigned short u16v2 __attribute__((ext_vector_type(2)));

template<int CTRL>
__device__ __forceinline__ int dpp_i(int x) {
  return __builtin_amdgcn_update_dpp(x, x, CTRL, 0xF, 0xF, true);
}
template<int CTRL>
__device__ __forceinline__ float dpp_f(float x) {
  return __int_as_float(dpp_i<CTRL>(__float_as_int(x)));
}
__device__ __forceinline__ float swz16_f(float x) {
  return __int_as_float(__builtin_amdgcn_ds_swizzle(__float_as_int(x), 0x401F));
}
__device__ __forceinline__ int pkminu16(int a, int b) {
  u16v2 av = *(u16v2*)&a, bv = *(u16v2*)&b;
  u16v2 r = __builtin_elementwise_min(av, bv);
  return *(int*)&r;
}
// barrier that drains LDS only (not vmcnt) — keeps prefetch loads in flight
#define BARRIER_LGKM() asm volatile("s_waitcnt lgkmcnt(0)\ns_barrier" ::: "memory")

// ============================================================================
// Phase 1: viterbi WITHOUT argmax scan — streams the pre-emission max vector
// m_t (NOT alpha) to global; + forward (log-norm) unchanged.  (VERIFIED R5)
// ============================================================================
__global__ __launch_bounds__(512, 4) void crf_fwd(
    const float* __restrict__ logits,     // [B,T,K]
    const int* __restrict__ labels,       // [B,T]
    const int* __restrict__ seq_lens,     // [B]
    const float* __restrict__ trans,      // [K,K]
    float* __restrict__ negll,            // [B] in ws
    int* __restrict__ lastIdx,            // [B] in ws
    float* __restrict__ mOut)             // [B][T][K] in ws (t>=1 valid)
{
  const int tid = threadIdx.x;
  const int cg = tid >> 3, rg = tid & 7;
  const int j0 = cg * 2, i0 = rg * 16;

  if (blockIdx.x < BB) {
    // ================= VITERBI (scan-free, m streamed) =================
    const int b = blockIdx.x;
    const int L = seq_lens[b];
    __shared__ __align__(16) float av[2][144];
    __shared__ float rv[8]; __shared__ int ri[8];

    v2f tv[16];
#pragma unroll
    for (int ii = 0; ii < 16; ++ii)
      tv[ii] = *(const v2f*)&trans[(i0 + ii) * KK + j0];

    if (tid < KK) av[0][AIDX(tid)] = logits[(b * TT) * KK + tid];

    v2f emC[4], emN[4];
#pragma unroll
    for (int s = 0; s < 4; ++s) {
      int t2 = 1 + s; if (t2 > L - 1) t2 = (L > 1) ? (L - 1) : 0;
      emC[s] = *(const v2f*)&logits[(b * TT + t2) * KK + j0];
    }
    __syncthreads();

    for (int tc = 1; tc < L; tc += 4) {
#pragma unroll
      for (int s = 0; s < 4; ++s) {
        int t2 = tc + 4 + s; if (t2 > L - 1) t2 = L - 1;
        emN[s] = *(const v2f*)&logits[(b * TT + t2) * KK + j0];
      }
#pragma unroll
      for (int s = 0; s < 4; ++s) {
        const int t = tc + s;
        if (t >= L) break;
        const float4* avr = (const float4*)(av[(t & 1) ^ 1] + AIDX(i0));
        v2f sv[16];
#pragma unroll
        for (int q = 0; q < 4; ++q) {
          float4 a4 = avr[q];
#pragma unroll
          for (int c = 0; c < 4; ++c) {
            float a = (c == 0) ? a4.x : (c == 1) ? a4.y : (c == 2) ? a4.z : a4.w;
            sv[q * 4 + c] = (v2f){a, a} + tv[q * 4 + c];   // exact IEEE adds
          }
        }
        // in-thread max tree (exact; max is order-insensitive, returns operand bits)
        v2f m;
        {
          v2f m0 = __builtin_elementwise_max(sv[0], sv[1]);
          v2f m1 = __builtin_elementwise_max(sv[2], sv[3]);
          v2f m2 = __builtin_elementwise_max(sv[4], sv[5]);
          v2f m3 = __builtin_elementwise_max(sv[6], sv[7]);
          v2f m4 = __builtin_elementwise_max(sv[8], sv[9]);
          v2f m5 = __builtin_elementwise_max(sv[10], sv[11]);
          v2f m6 = __builtin_elementwise_max(sv[12], sv[13]);
          v2f m7 = __builtin_elementwise_max(sv[14], sv[15]);
          m0 = __builtin_elementwise_max(m0, m1);
          m2 = __builtin_elementwise_max(m2, m3);
          m4 = __builtin_elementwise_max(m4, m5);
          m6 = __builtin_elementwise_max(m6, m7);
          m0 = __builtin_elementwise_max(m0, m2);
          m4 = __builtin_elementwise_max(m4, m6);
          m = __builtin_elementwise_max(m0, m4);
        }
        // cross-row-group max: xor1, xor2, xor4 — all DPP
        {
          v2f o;
          o.x = dpp_f<0xB1>(m.x); o.y = dpp_f<0xB1>(m.y);
          m = __builtin_elementwise_max(m, o);
          o.x = dpp_f<0x4E>(m.x); o.y = dpp_f<0x4E>(m.y);
          m = __builtin_elementwise_max(m, o);
          o.x = dpp_f<0x141>(m.x); o.y = dpp_f<0x141>(m.y);
          m = __builtin_elementwise_max(m, o);
        }
        v2f nav = m + emC[s];
        if (rg == 0) {
          *(v2f*)(av[t & 1] + AIDX(j0)) = nav;
          *(v2f*)&mOut[(b * TT + t) * KK + j0] = m;   // stream m_t
        }
        BARRIER_LGKM();
      }
#pragma unroll
      for (int s = 0; s < 4; ++s) emC[s] = emN[s];
    }

    // final argmax across K → lastIdx
    const float* avf = av[(L - 1) & 1];
    {
      float v = (tid < KK) ? avf[AIDX(tid)] : -3.4e38f;
      int idx = (tid < KK) ? tid : KK;
#pragma unroll
      for (int mm = 1; mm < 64; mm <<= 1) {
        float ov = __shfl_xor(v, mm);
        int oi = __shfl_xor(idx, mm);
        if (ov > v || (ov == v && oi < idx)) { v = ov; idx = oi; }
      }
      if ((tid & 63) == 0) { rv[tid >> 6] = v; ri[tid >> 6] = idx; }
    }
    __syncthreads();
    if (tid == 0) {
      float bv = rv[0]; int bi = ri[0];
#pragma unroll
      for (int w = 1; w < 8; ++w)
        if (rv[w] > bv || (rv[w] == bv && ri[w] < bi)) { bv = rv[w]; bi = ri[w]; }
      lastIdx[b] = bi;
    }

  } else {
    // ================= FORWARD (log-norm) — unchanged from 438us baseline ===
    const int b = blockIdx.x - BB;
    const int L = seq_lens[b];
    __shared__ __align__(16) float ev[2][144];
    __shared__ __align__(16) float wmax[16];
    __shared__ float rs[8]; __shared__ float rsc[8];

    v2f tw[16];
#pragma unroll
    for (int ii = 0; ii < 16; ++ii) {
      v2f tr = *(const v2f*)&trans[(i0 + ii) * KK + j0];
      tw[ii].x = __expf(tr.x);
      tw[ii].y = __expf(tr.y);
    }
    if (tid < KK) ev[0][AIDX(tid)] = __expf(logits[(b * TT) * KK + tid]);
    if (tid < 16) wmax[tid] = 1.0f;

    v2f emC[4], emN[4];
#pragma unroll
    for (int s = 0; s < 4; ++s) {
      int t2 = 1 + s; if (t2 > L - 1) t2 = (L > 1) ? (L - 1) : 0;
      emC[s] = *(const v2f*)&logits[(b * TT + t2) * KK + j0];
    }
    __syncthreads();

    float Cln = 0.0f;
    for (int tc = 1; tc < L; tc += 4) {
#pragma unroll
      for (int s = 0; s < 4; ++s) {
        int t2 = tc + 4 + s; if (t2 > L - 1) t2 = L - 1;
        emN[s] = *(const v2f*)&logits[(b * TT + t2) * KK + j0];
      }
      // renorm factor (exact pow2), once per 4-step chunk
      float r;
      {
        float4 w0 = *(const float4*)&wmax[0];
        float4 w1 = *(const float4*)&wmax[4];
        float4 w2 = *(const float4*)&wmax[8];
        float4 w3 = *(const float4*)&wmax[12];
        float U = fmaxf(fmaxf(fmaxf(w0.x, w0.y), fmaxf(w0.z, w0.w)),
                        fmaxf(fmaxf(w1.x, w1.y), fmaxf(w1.z, w1.w)));
        U = fmaxf(U, fmaxf(fmaxf(fmaxf(w2.x, w2.y), fmaxf(w2.z, w2.w)),
                           fmaxf(fmaxf(w3.x, w3.y), fmaxf(w3.z, w3.w))));
        int ex = (__float_as_int(U) >> 23) & 255;
        r = __int_as_float((254 - ex) << 23);
        Cln += (float)(ex - 127) * 0.6931471805599453f;
      }
#pragma unroll
      for (int s = 0; s < 4; ++s) {
        const int t = tc + s;
        if (t >= L) break;
        const float4* evr = (const float4*)(ev[(t & 1) ^ 1] + AIDX(i0));
        v2f S2 = {0.0f, 0.0f};
#pragma unroll
        for (int q = 0; q < 4; ++q) {
          float4 e4 = evr[q];
#pragma unroll
          for (int c = 0; c < 4; ++c) {
            float e = (c == 0) ? e4.x : (c == 1) ? e4.y : (c == 2) ? e4.z : e4.w;
            S2 += (v2f){e, e} * tw[q * 4 + c];   // pk_fma
          }
        }
        {
          v2f o;
          o.x = dpp_f<0xB1>(S2.x); o.y = dpp_f<0xB1>(S2.y); S2 += o;
          o.x = dpp_f<0x4E>(S2.x); o.y = dpp_f<0x4E>(S2.y); S2 += o;
          o.x = dpp_f<0x141>(S2.x); o.y = dpp_f<0x141>(S2.y); S2 += o;
        }
        v2f em2 = emC[s];
        float evn0 = S2.x * __expf(em2.x);
        float evn1 = S2.y * __expf(em2.y);
        if (s == 0) { evn0 *= r; evn1 *= r; }
        if (rg == 0)
          *(v2f*)(ev[t & 1] + AIDX(j0)) = (v2f){evn0, evn1};
        if (s == 3) {
          float wm = fmaxf(evn0, evn1);
          wm = fmaxf(wm, dpp_f<0x140>(wm));   // xor8 (values 8-uniform)
          wm = fmaxf(wm, swz16_f(wm));        // xor16
          if ((tid & 31) == 0) wmax[tid >> 5] = wm;
        }
        BARRIER_LGKM();
      }
#pragma unroll
      for (int s = 0; s < 4; ++s) emC[s] = emN[s];
    }

    const float* evf = ev[(L - 1) & 1];
    {
      float ssum = (tid < KK) ? evf[AIDX(tid)] : 0.0f;
#pragma unroll
      for (int mm = 1; mm < 64; mm <<= 1) ssum += __shfl_xor(ssum, mm);
      if ((tid & 63) == 0) rs[tid >> 6] = ssum;
    }
    float sc = 0.0f;
    for (int tt2 = tid; tt2 < L; tt2 += 512) {
      int lab = labels[b * TT + tt2];
      sc += logits[(b * TT + tt2) * KK + lab];
      if (tt2 >= 1) sc += trans[labels[b * TT + tt2 - 1] * KK + lab];
    }
#pragma unroll
    for (int mm = 1; mm < 64; mm <<= 1) sc += __shfl_xor(sc, mm);
    if ((tid & 63) == 0) rsc[tid >> 6] = sc;
    __syncthreads();
    if (tid == 0) {
      float es = rs[0]; float scf = rsc[0];
#pragma unroll
      for (int w = 1; w < 8; ++w) { es += rs[w]; scf += rsc[w]; }
      negll[b] = (Cln + logf(es)) - scf;
    }
  }
}

// ============================================================================
// Phase 2: backtrack via EQUALITY MATCH (semantics verified in R5).
// NEW: software-pipelined prefetch — 8-deep, UNCONDITIONAL clamped loads,
// static stage indices (unrolled 8-phase main loop) so the compiler emits
// counted vmcnt instead of per-iteration vmcnt(0) drains.
// Per-step dep chain: tag -> {readlane m_t[tag] || ds_read tT[tag] row}
// -> add/cmp -> ballot -> ffs -> readlane.  (~170 cyc; memory ~lat/8.)
// ============================================================================
__global__ __launch_bounds__(64, 1) void crf_backtrack(
    const float* __restrict__ mvec,       // [B][T][K] in ws (t>=1 valid)
    const float* __restrict__ logits,     // [B,T,K]
    const int* __restrict__ seq_lens,     // [B]
    const int* __restrict__ lastIdx,      // [B] in ws
    const float* __restrict__ trans,      // [K,K]
    float* __restrict__ pred_out)         // [B,T] as float
{
  const int b = blockIdx.x, l = threadIdx.x;
  const int L = seq_lens[b];
  __shared__ float tT[KK][KK + 2];        // transposed trans; row stride 520 B
  __shared__ float tagsf[TT];

  // build transpose (one-time)
  for (int i = 0; i < KK; ++i) {
    v2f r = *(const v2f*)&trans[i * KK + 2 * l];
    tT[2 * l][i] = r.x;
    tT[2 * l + 1][i] = r.y;
  }
  const int last = lastIdx[b];
  for (int t = l; t < TT; t += 64) tagsf[t] = (float)last;   // t >= L-1 keeps last
  __syncthreads();

  if (L >= 2) {
    const float* mb = mvec   + (size_t)(b * TT) * KK + 2 * l;
    const float* gb = logits + (size_t)(b * TT) * KK + 2 * l;
    int tag = last;
    v2f mvC = *(const v2f*)&mb[(size_t)(L - 1) * KK];   // m at current step t

    // 8-deep pipeline: stage p holds (logits,m) rows for time t-1-p at loop top.
    // Loads are UNCONDITIONAL with addresses clamped to row 0; clamped/garbage
    // rows are either never consumed or discarded by the tp>=1 select in the
    // epilogue. (mvec row 0 is uninitialized — only ever read, never used.)
    v2f lg0, lg1, lg2, lg3, lg4, lg5, lg6, lg7;
    v2f mv0, mv1, mv2, mv3, mv4, mv5, mv6, mv7;
#define INITLD(P) { int s_ = L - 2 - (P); int sc_ = s_ < 0 ? 0 : s_;            \
      lg##P = *(const v2f*)&gb[(size_t)sc_ * KK];                              \
      mv##P = *(const v2f*)&mb[(size_t)sc_ * KK]; }
    INITLD(0) INITLD(1) INITLD(2) INITLD(3)
    INITLD(4) INITLD(5) INITLD(6) INITLD(7)
#undef INITLD

    int t = L - 1;

#define STEP_BODY(LG, MV, GUARDED)                                             \
    {                                                                          \
      const int tp = t - 1;                                                    \
      v2f aP;                                                                  \
      if (GUARDED) aP = (tp >= 1) ? (MV + LG) : LG;                            \
      else         aP = MV + LG;                                               \
      int lanem = tag >> 1;                                                    \
      int txi = __builtin_amdgcn_readlane(__float_as_int(mvC.x), lanem);       \
      int tyi = __builtin_amdgcn_readlane(__float_as_int(mvC.y), lanem);       \
      float target = __int_as_float((tag & 1) ? tyi : txi);                    \
      v2f col = *(const v2f*)&tT[tag][2 * l];                                  \
      v2f sv = aP + col;                 /* bit-exact phase-1 adds */          \
      bool h0 = (sv.x == target), h1 = (sv.y == target);                       \
      unsigned long long mask = __ballot(h0 || h1);                            \
      int first = __ffsll(mask) - 1;     /* lowest matching lane */            \
      int cand = h0 ? (2 * l) : (2 * l + 1);                                   \
      tag = __builtin_amdgcn_readlane(cand, first);                            \
      if (l == 0) tagsf[tp] = (float)tag;                                      \
      mvC = MV;                                                                \
    }

    // main loop: 8 steps per group, all tp>=1, refill stage p with time t-9
    while (t >= 9) {
#define MAIN_PHASE(P)                                                          \
      STEP_BODY(lg##P, mv##P, false)                                           \
      { int sN = t - 9; int sc_ = sN < 0 ? 0 : sN;                             \
        lg##P = *(const v2f*)&gb[(size_t)sc_ * KK];                            \
        mv##P = *(const v2f*)&mb[(size_t)sc_ * KK]; }                          \
      --t;
      MAIN_PHASE(0) MAIN_PHASE(1) MAIN_PHASE(2) MAIN_PHASE(3)
      MAIN_PHASE(4) MAIN_PHASE(5) MAIN_PHASE(6) MAIN_PHASE(7)
#undef MAIN_PHASE
    }

    // epilogue: <=8 remaining steps, direct loads, tp==0 guard
    while (t >= 1) {
      const int tp = t - 1;
      int sc_ = tp < 1 ? 0 : tp;
      v2f lgE = *(const v2f*)&gb[(size_t)tp * KK];
      v2f mvE = *(const v2f*)&mb[(size_t)sc_ * KK];
      STEP_BODY(lgE, mvE, true)
      --t;
    }
#undef STEP_BODY
  }
  __syncthreads();
#pragma unroll
  for (int k = 0; k < 8; ++k)
    pred_out[b * TT + l * 8 + k] = tagsf[l * 8 + k];
}

// ============================================================================
// FALLBACK: verbatim 438us two-block kernel (bp in ws), used if ws too small.
// ============================================================================
__global__ __launch_bounds__(512, 4) void crf_main_fb(
    const float* __restrict__ logits,
    const int* __restrict__ labels,
    const int* __restrict__ seq_lens,
    const float* __restrict__ trans,
    float* __restrict__ pred_out,
    float* __restrict__ negll,
    unsigned char* __restrict__ bp)
{
  const int tid = threadIdx.x;
  const int cg = tid >> 3, rg = tid & 7;
  const int j0 = cg * 2, i0 = rg * 16;

  if (blockIdx.x < BB) {
    const int b = blockIdx.x;
    const int L = seq_lens[b];
    __shared__ __align__(16) float av[2][144];
    __shared__ unsigned char tags[TT];
    __shared__ float rv[8]; __shared__ int ri[8];
    __shared__ int last_s;

    v2f tv[16];
#pragma unroll
    for (int ii = 0; ii < 16; ++ii)
      tv[ii] = *(const v2f*)&trans[(i0 + ii) * KK + j0];

    if (tid < KK) av[0][AIDX(tid)] = logits[(b * TT) * KK + tid];

    v2f emC[4], emN[4];
#pragma unroll
    for (int s = 0; s < 4; ++s) {
      int t2 = 1 + s; if (t2 > L - 1) t2 = (L > 1) ? (L - 1) : 0;
      emC[s] = *(const v2f*)&logits[(b * TT + t2) * KK + j0];
    }
    __syncthreads();

    unsigned int pw0 = 0, pw1 = 0; int pend_c = -1;

    for (int tc = 1; tc < L; tc += 4) {
#pragma unroll
      for (int s = 0; s < 4; ++s) {
        int t2 = tc + 4 + s; if (t2 > L - 1) t2 = L - 1;
        emN[s] = *(const v2f*)&logits[(b * TT + t2) * KK + j0];
      }
      if (pend_c >= 0 && rg == 1) {
        *(uint2*)(bp + (((b << 7) + pend_c) << 9) + (cg << 3)) =
            make_uint2(pw0, pw1);
      }
      unsigned int w0 = 0, w1 = 0;
#pragma unroll
      for (int s = 0; s < 4; ++s) {
        const int t = tc + s;
        if (t >= L) break;
        const float4* avr = (const float4*)(av[(t & 1) ^ 1] + AIDX(i0));
        v2f sv[16];
#pragma unroll
        for (int q = 0; q < 4; ++q) {
          float4 a4 = avr[q];
#pragma unroll
          for (int c = 0; c < 4; ++c) {
            float a = (c == 0) ? a4.x : (c == 1) ? a4.y : (c == 2) ? a4.z : a4.w;
            sv[q * 4 + c] = (v2f){a, a} + tv[q * 4 + c];
          }
        }
        v2f m;
        {
          v2f m0 = __builtin_elementwise_max(sv[0], sv[1]);
          v2f m1 = __builtin_elementwise_max(sv[2], sv[3]);
          v2f m2 = __builtin_elementwise_max(sv[4], sv[5]);
          v2f m3 = __builtin_elementwise_max(sv[6], sv[7]);
          v2f m4 = __builtin_elementwise_max(sv[8], sv[9]);
          v2f m5 = __builtin_elementwise_max(sv[10], sv[11]);
          v2f m6 = __builtin_elementwise_max(sv[12], sv[13]);
          v2f m7 = __builtin_elementwise_max(sv[14], sv[15]);
          m0 = __builtin_elementwise_max(m0, m1);
          m2 = __builtin_elementwise_max(m2, m3);
          m4 = __builtin_elementwise_max(m4, m5);
          m6 = __builtin_elementwise_max(m6, m7);
          m0 = __builtin_elementwise_max(m0, m2);
          m4 = __builtin_elementwise_max(m4, m6);
          m = __builtin_elementwise_max(m0, m4);
        }
        {
          v2f o;
          o.x = dpp_f<0xB1>(m.x); o.y = dpp_f<0xB1>(m.y);
          m = __builtin_elementwise_max(m, o);
          o.x = dpp_f<0x4E>(m.x); o.y = dpp_f<0x4E>(m.y);
          m = __builtin_elementwise_max(m, o);
          o.x = dpp_f<0x141>(m.x); o.y = dpp_f<0x141>(m.y);
          m = __builtin_elementwise_max(m, o);
        }
        int ai0 = 0xFFFF, ai1 = 0xFFFF;
#pragma unroll
        for (int i = 15; i >= 0; --i) {
          ai0 = (sv[i].x == m.x) ? (i0 + i) : ai0;
          ai1 = (sv[i].y == m.y) ? (i0 + i) : ai1;
        }
        int aip = ai0 | (ai1 << 16);
        aip = pkminu16(aip, dpp_i<0xB1>(aip));
        aip = pkminu16(aip, dpp_i<0x4E>(aip));
        aip = pkminu16(aip, dpp_i<0x141>(aip));

        v2f em2 = emC[s];
        if (rg == 0)
          *(v2f*)(av[t & 1] + AIDX(j0)) = m + em2;
        unsigned int pk = ((unsigned int)aip & 0xFFu) |
                          (((unsigned int)aip >> 8) & 0xFF00u);
        unsigned int sh = pk << ((s & 1) * 16);
        if (s < 2) w0 |= sh; else w1 |= sh;
        BARRIER_LGKM();
      }
      pw0 = w0; pw1 = w1; pend_c = (tc - 1) >> 2;
#pragma unroll
      for (int s = 0; s < 4; ++s) emC[s] = emN[s];
    }
    if (pend_c >= 0 && rg == 1) {
      *(uint2*)(bp + (((b << 7) + pend_c) << 9) + (cg << 3)) =
          make_uint2(pw0, pw1);
    }

    const float* avf = av[(L - 1) & 1];
    {
      float v = (tid < KK) ? avf[AIDX(tid)] : -3.4e38f;
      int idx = (tid < KK) ? tid : KK;
#pragma unroll
      for (int mm = 1; mm < 64; mm <<= 1) {
        float ov = __shfl_xor(v, mm);
        int oi = __shfl_xor(idx, mm);
        if (ov > v || (ov == v && oi < idx)) { v = ov; idx = oi; }
      }
      if ((tid & 63) == 0) { rv[tid >> 6] = v; ri[tid >> 6] = idx; }
    }
    __syncthreads();
    if (tid == 0) {
      float bv = rv[0]; int bi = ri[0];
#pragma unroll
      for (int w = 1; w < 8; ++w)
        if (rv[w] > bv || (rv[w] == bv && ri[w] < bi)) { bv = rv[w]; bi = ri[w]; }
      last_s = bi;
    }
    __syncthreads();
    const int last = last_s;
    if (tid >= L - 1 && tid < TT) tags[tid] = (unsigned char)last;
    __syncthreads();

    if (tid < 64 && L >= 2) {
      const uint2* bpv = (const uint2*)bp;
      int tag = last;
      int cTop = (L - 2) >> 2;
      uint2 q = bpv[(((b << 7) + cTop) << 6) + tid];
      for (int c = cTop; c >= 0; --c) {
        uint2 qn;
        if (c > 0) qn = bpv[(((b << 7) + (c - 1)) << 6) + tid];
        int sHi = (L - 2) - 4 * c; if (sHi > 3) sHi = 3;
#pragma unroll
        for (int s = 3; s >= 0; --s) {
          if (s <= sHi) {
            int word = (s < 2) ? (int)q.x : (int)q.y;
            unsigned int w = (unsigned int)__shfl(word, tag >> 1);
            tag = (int)((w >> ((((s & 1) << 1) | (tag & 1)) << 3)) & 255u);
            if (tid == 0) tags[4 * c + s] = (unsigned char)tag;
          }
        }
        q = qn;
      }
    }
    __syncthreads();
    pred_out[b * TT + tid] = (float)tags[tid];

  } else {
    const int b = blockIdx.x - BB;
    const int L = seq_lens[b];
    __shared__ __align__(16) float ev[2][144];
    __shared__ __align__(16) float wmax[16];
    __shared__ float rs[8]; __shared__ float rsc[8];

    v2f tw[16];
#pragma unroll
    for (int ii = 0; ii < 16; ++ii) {
      v2f tr = *(const v2f*)&trans[(i0 + ii) * KK + j0];
      tw[ii].x = __expf(tr.x);
      tw[ii].y = __expf(tr.y);
    }
    if (tid < KK) ev[0][AIDX(tid)] = __expf(logits[(b * TT) * KK + tid]);
    if (tid < 16) wmax[tid] = 1.0f;

    v2f emC[4], emN[4];
#pragma unroll
    for (int s = 0; s < 4; ++s) {
      int t2 = 1 + s; if (t2 > L - 1) t2 = (L > 1) ? (L - 1) : 0;
      emC[s] = *(const v2f*)&logits[(b * TT + t2) * KK + j0];
    }
    __syncthreads();

    float Cln = 0.0f;
    for (int tc = 1; tc < L; tc += 4) {
#pragma unroll
      for (int s = 0; s < 4; ++s) {
        int t2 = tc + 4 + s; if (t2 > L - 1) t2 = L - 1;
        emN[s] = *(const v2f*)&logits[(b * TT + t2) * KK + j0];
      }
      float r;
      {
        float4 w0 = *(const float4*)&wmax[0];
        float4 w1 = *(const float4*)&wmax[4];
        float4 w2 = *(const float4*)&wmax[8];
        float4 w3 = *(const float4*)&wmax[12];
        float U = fmaxf(fmaxf(fmaxf(w0.x, w0.y), fmaxf(w0.z, w0.w)),
                        fmaxf(fmaxf(w1.x, w1.y), fmaxf(w1.z, w1.w)));
        U = fmaxf(U, fmaxf(fmaxf(fmaxf(w2.x, w2.y), fmaxf(w2.z, w2.w)),
                           fmaxf(fmaxf(w3.x, w3.y), fmaxf(w3.z, w3.w))));
        int ex = (__float_as_int(U) >> 23) & 255;
        r = __int_as_float((254 - ex) << 23);
        Cln += (float)(ex - 127) * 0.6931471805599453f;
      }
#pragma unroll
      for (int s = 0; s < 4; ++s) {
        const int t = tc + s;
        if (t >= L) break;
        const float4* evr = (const float4*)(ev[(t & 1) ^ 1] + AIDX(i0));
        v2f S2 = {0.0f, 0.0f};
#pragma unroll
        for (int q = 0; q < 4; ++q) {
          float4 e4 = evr[q];
#pragma unroll
          for (int c = 0; c < 4; ++c) {
            float e = (c == 0) ? e4.x : (c == 1) ? e4.y : (c == 2) ? e4.z : e4.w;
            S2 += (v2f){e, e} * tw[q * 4 + c];
          }
        }
        {
          v2f o;
          o.x = dpp_f<0xB1>(S2.x); o.y = dpp_f<0xB1>(S2.y); S2 += o;
          o.x = dpp_f<0x4E>(S2.x); o.y = dpp_f<0x4E>(S2.y); S2 += o;
          o.x = dpp_f<0x141>(S2.x); o.y = dpp_f<0x141>(S2.y); S2 += o;
        }
        v2f em2 = emC[s];
        float evn0 = S2.x * __expf(em2.x);
        float evn1 = S2.y * __expf(em2.y);
        if (s == 0) { evn0 *= r; evn1 *= r; }
        if (rg == 0)
          *(v2f*)(ev[t & 1] + AIDX(j0)) = (v2f){evn0, evn1};
        if (s == 3) {
          float wm = fmaxf(evn0, evn1);
          wm = fmaxf(wm, dpp_f<0x140>(wm));
          wm = fmaxf(wm, swz16_f(wm));
          if ((tid & 31) == 0) wmax[tid >> 5] = wm;
        }
        BARRIER_LGKM();
      }
#pragma unroll
      for (int s = 0; s < 4; ++s) emC[s] = emN[s];
    }

    const float* evf = ev[(L - 1) & 1];
    {
      float ssum = (tid < KK) ? evf[AIDX(tid)] : 0.0f;
#pragma unroll
      for (int mm = 1; mm < 64; mm <<= 1) ssum += __shfl_xor(ssum, mm);
      if ((tid & 63) == 0) rs[tid >> 6] = ssum;
    }
    float sc = 0.0f;
    for (int tt2 = tid; tt2 < L; tt2 += 512) {
      int lab = labels[b * TT + tt2];
      sc += logits[(b * TT + tt2) * KK + lab];
      if (tt2 >= 1) sc += trans[labels[b * TT + tt2 - 1] * KK + lab];
    }
#pragma unroll
    for (int mm = 1; mm < 64; mm <<= 1) sc += __shfl_xor(sc, mm);
    if ((tid & 63) == 0) rsc[tid >> 6] = sc;
    __syncthreads();
    if (tid == 0) {
      float es = rs[0]; float scf = rsc[0];
#pragma unroll
      for (int w = 1; w < 8; ++w) { es += rs[w]; scf += rsc[w]; }
      negll[b] = (Cln + logf(es)) - scf;
    }
  }
}

__global__ void crf_loss_reduce(const float* __restrict__ negll, float* __restrict__ out) {
  int tid = threadIdx.x;
  float v = negll[tid];
#pragma unroll
  for (int m = 1; m < 64; m <<= 1) v += __shfl_xor(v, m);
  __shared__ float p[4];
  if ((tid & 63) == 0) p[tid >> 6] = v;
  __syncthreads();
  if (tid == 0) out[0] = p[0] + p[1] + p[2] + p[3];
}

extern "C" void kernel_launch(void* const* d_in, const int* in_sizes, int n_in,
                              void* d_out, int out_size, void* d_ws, size_t ws_size,
                              hipStream_t stream) {
  const float* logits   = (const float*)d_in[0];
  const int*   labels   = (const int*)d_in[1];
  const int*   seq_lens = (const int*)d_in[2];
  const float* trans    = (const float*)d_in[3];
  float* out = (float*)d_out;

  float* negll = (float*)d_ws;                          // [0, 1KB): 256 floats
  const size_t M_OFF = 4096;
  const size_t NEED = M_OFF + (size_t)BB * TT * KK * 4;   // ~67.1 MB

  if (ws_size >= NEED) {
    int*   lastIdx = (int*)((char*)d_ws + 1024);        // [1KB, 2KB)
    float* mOut    = (float*)((char*)d_ws + M_OFF);     // [4KB, 4KB+67.1MB)
    crf_fwd<<<2 * BB, 512, 0, stream>>>(logits, labels, seq_lens, trans,
                                        negll, lastIdx, mOut);
    crf_backtrack<<<BB, 64, 0, stream>>>(mOut, logits, seq_lens, lastIdx,
                                         trans, out + 1);
  } else {
    unsigned char* bp = (unsigned char*)d_ws + 1024;    // 16.8 MB
    crf_main_fb<<<2 * BB, 512, 0, stream>>>(logits, labels, seq_lens, trans,
                                            out + 1, negll, bp);
  }
  crf_loss_reduce<<<1, 256, 0, stream>>>(negll, out);
}

// Round 7
// 381.063 us; speedup vs baseline: 1.7602x; 1.1423x over previous
//
#include <hip/hip_runtime.h>
#include <math.h>

#define BB 256
#define TT 512
#define KK 128
#define AIDX(i) ((i) + (((i) >> 5) << 2))

// shared-memory layout (floats) for the fused kernel
#define SM_TT    0          // [128][130] transposed trans = 16640
#define SM_AV    16640      // av[2][144] = 288   (vit)  | ev[2][144] (fwd)
#define SM_TAGS  16928      // tagsf[512]
#define SM_RV    17440      // rv[8]
#define SM_RI    17448      // ri[8]
#define SM_LAST  17456      // last_s
#define SM_WMAX  17460      // wmax[16] (fwd)
#define SM_RS    17476      // rs[8]   (fwd)
#define SM_RSC   17484      // rsc[8]  (fwd)
#define SM_TOTAL 17496      // ~70.0 KB -> 2 blocks/CU

typedef float v2f __attribute__((ext_vector_type(2)));
typedef unsigned short u16v2 __attribute__((ext_vector_type(2)));

template<int CTRL>
__device__ __forceinline__ int dpp_i(int x) {
  return __builtin_amdgcn_update_dpp(x, x, CTRL, 0xF, 0xF, true);
}
template<int CTRL>
__device__ __forceinline__ float dpp_f(float x) {
  return __int_as_float(dpp_i<CTRL>(__float_as_int(x)));
}
__device__ __forceinline__ float swz16_f(float x) {
  return __int_as_float(__builtin_amdgcn_ds_swizzle(__float_as_int(x), 0x401F));
}
__device__ __forceinline__ int pkminu16(int a, int b) {
  u16v2 av = *(u16v2*)&a, bv = *(u16v2*)&b;
  u16v2 r = __builtin_elementwise_min(av, bv);
  return *(int*)&r;
}
// barrier that drains LDS only (not vmcnt) — keeps prefetch loads in flight
#define BARRIER_LGKM() asm volatile("s_waitcnt lgkmcnt(0)\ns_barrier" ::: "memory")

// ============================================================================
// FUSED kernel: blocks [0,BB): scan-free viterbi recursion (streams m_t) then
// wave 0 runs the equality-match backtrack chase in-block (waves 1-7 retire,
// freeing the CU; chase overlaps other blocks' recursions). Blocks [BB,2BB):
// forward log-norm (verbatim). One barrier structure per chain as verified.
// ============================================================================
__global__ __launch_bounds__(512, 4) void crf_main(
    const float* __restrict__ logits,     // [B,T,K]
    const int* __restrict__ labels,       // [B,T]
    const int* __restrict__ seq_lens,     // [B]
    const float* __restrict__ trans,      // [K,K]
    float* __restrict__ pred_out,         // [B,T] as float (d_out+1)
    float* __restrict__ negll,            // [B] in ws
    float* __restrict__ mOut)             // [B][T][K] in ws (t>=1 valid)
{
  __shared__ __align__(16) float smem[SM_TOTAL];
  const int tid = threadIdx.x;
  const int cg = tid >> 3, rg = tid & 7;
  const int j0 = cg * 2, i0 = rg * 16;

  if (blockIdx.x < BB) {
    // ================= VITERBI (scan-free) + in-block chase =================
    const int b = blockIdx.x;
    const int L = seq_lens[b];
    float* tT    = smem + SM_TT;                      // [128][130]
    float (*av)[144] = (float(*)[144])(smem + SM_AV);
    float* tagsf = smem + SM_TAGS;
    float* rv    = smem + SM_RV;
    int*   ri    = (int*)(smem + SM_RI);
    int*   last_s = (int*)(smem + SM_LAST);

    // build transposed trans for the chase (coalesced reads, one-time)
    for (int e = tid; e < KK * KK; e += 512) {
      int i = e >> 7, j = e & 127;
      tT[j * 130 + i] = trans[e];
    }

    v2f tv[16];
#pragma unroll
    for (int ii = 0; ii < 16; ++ii)
      tv[ii] = *(const v2f*)&trans[(i0 + ii) * KK + j0];

    if (tid < KK) av[0][AIDX(tid)] = logits[(b * TT) * KK + tid];

    v2f emC[4], emN[4];
#pragma unroll
    for (int s = 0; s < 4; ++s) {
      int t2 = 1 + s; if (t2 > L - 1) t2 = (L > 1) ? (L - 1) : 0;
      emC[s] = *(const v2f*)&logits[(b * TT + t2) * KK + j0];
    }
    __syncthreads();

    for (int tc = 1; tc < L; tc += 4) {
#pragma unroll
      for (int s = 0; s < 4; ++s) {
        int t2 = tc + 4 + s; if (t2 > L - 1) t2 = L - 1;
        emN[s] = *(const v2f*)&logits[(b * TT + t2) * KK + j0];
      }
#pragma unroll
      for (int s = 0; s < 4; ++s) {
        const int t = tc + s;
        if (t >= L) break;
        const float4* avr = (const float4*)(av[(t & 1) ^ 1] + AIDX(i0));
        v2f sv[16];
#pragma unroll
        for (int q = 0; q < 4; ++q) {
          float4 a4 = avr[q];
#pragma unroll
          for (int c = 0; c < 4; ++c) {
            float a = (c == 0) ? a4.x : (c == 1) ? a4.y : (c == 2) ? a4.z : a4.w;
            sv[q * 4 + c] = (v2f){a, a} + tv[q * 4 + c];   // exact IEEE adds
          }
        }
        // in-thread max tree (exact; max is order-insensitive, returns operand bits)
        v2f m;
        {
          v2f m0 = __builtin_elementwise_max(sv[0], sv[1]);
          v2f m1 = __builtin_elementwise_max(sv[2], sv[3]);
          v2f m2 = __builtin_elementwise_max(sv[4], sv[5]);
          v2f m3 = __builtin_elementwise_max(sv[6], sv[7]);
          v2f m4 = __builtin_elementwise_max(sv[8], sv[9]);
          v2f m5 = __builtin_elementwise_max(sv[10], sv[11]);
          v2f m6 = __builtin_elementwise_max(sv[12], sv[13]);
          v2f m7 = __builtin_elementwise_max(sv[14], sv[15]);
          m0 = __builtin_elementwise_max(m0, m1);
          m2 = __builtin_elementwise_max(m2, m3);
          m4 = __builtin_elementwise_max(m4, m5);
          m6 = __builtin_elementwise_max(m6, m7);
          m0 = __builtin_elementwise_max(m0, m2);
          m4 = __builtin_elementwise_max(m4, m6);
          m = __builtin_elementwise_max(m0, m4);
        }
        // cross-row-group max: xor1, xor2, xor4 — all DPP
        {
          v2f o;
          o.x = dpp_f<0xB1>(m.x); o.y = dpp_f<0xB1>(m.y);
          m = __builtin_elementwise_max(m, o);
          o.x = dpp_f<0x4E>(m.x); o.y = dpp_f<0x4E>(m.y);
          m = __builtin_elementwise_max(m, o);
          o.x = dpp_f<0x141>(m.x); o.y = dpp_f<0x141>(m.y);
          m = __builtin_elementwise_max(m, o);
        }
        v2f nav = m + emC[s];
        if (rg == 0) {
          *(v2f*)(av[t & 1] + AIDX(j0)) = nav;
          *(v2f*)&mOut[(b * TT + t) * KK + j0] = m;   // stream m_t
        }
        BARRIER_LGKM();
      }
#pragma unroll
      for (int s = 0; s < 4; ++s) emC[s] = emN[s];
    }

    // final argmax across K → last_s
    const float* avf = av[(L - 1) & 1];
    {
      float v = (tid < KK) ? avf[AIDX(tid)] : -3.4e38f;
      int idx = (tid < KK) ? tid : KK;
#pragma unroll
      for (int mm = 1; mm < 64; mm <<= 1) {
        float ov = __shfl_xor(v, mm);
        int oi = __shfl_xor(idx, mm);
        if (ov > v || (ov == v && oi < idx)) { v = ov; idx = oi; }
      }
      if ((tid & 63) == 0) { rv[tid >> 6] = v; ri[tid >> 6] = idx; }
    }
    __syncthreads();
    if (tid == 0) {
      float bv = rv[0]; int bi = ri[0];
#pragma unroll
      for (int w = 1; w < 8; ++w)
        if (rv[w] > bv || (rv[w] == bv && ri[w] < bi)) { bv = rv[w]; bi = ri[w]; }
      *last_s = bi;
    }
    __syncthreads();
    const int last = *last_s;
    // init all tags to last (chase overwrites 0..L-2)
    for (int t = tid; t < TT; t += 512) tagsf[t] = (float)last;
    // this barrier: (a) tagsf init visible to wave 0, (b) drains every wave's
    // vmcnt (compiler emits vmcnt(0) before s_barrier) so mOut writes are in L2
    __syncthreads();

    if (tid >= 64) return;        // waves 1-7 retire; wave 0 runs the chase
    const int l = tid;

    if (L >= 2) {
      const float* mb = mOut   + (size_t)(b * TT) * KK + 2 * l;
      const float* gb = logits + (size_t)(b * TT) * KK + 2 * l;
      int tag = last;
      v2f mvC = *(const v2f*)&mb[(size_t)(L - 1) * KK];   // m at current step t

      // 8-deep pipeline: stage p holds (logits,m) rows for time t-1-p at loop
      // top. Unconditional clamped loads; clamped rows never consumed unguarded.
      v2f lg0, lg1, lg2, lg3, lg4, lg5, lg6, lg7;
      v2f mv0, mv1, mv2, mv3, mv4, mv5, mv6, mv7;
#define INITLD(P) { int s_ = L - 2 - (P); int sc_ = s_ < 0 ? 0 : s_;           \
      lg##P = *(const v2f*)&gb[(size_t)sc_ * KK];                              \
      mv##P = *(const v2f*)&mb[(size_t)sc_ * KK]; }
      INITLD(0) INITLD(1) INITLD(2) INITLD(3)
      INITLD(4) INITLD(5) INITLD(6) INITLD(7)
#undef INITLD

      int t = L - 1;

#define STEP_BODY(LG, MV, GUARDED)                                             \
      {                                                                        \
        const int tp = t - 1;                                                  \
        v2f aP;                                                                \
        if (GUARDED) aP = (tp >= 1) ? (MV + LG) : LG;                          \
        else         aP = MV + LG;                                             \
        int lanem = tag >> 1;                                                  \
        int txi = __builtin_amdgcn_readlane(__float_as_int(mvC.x), lanem);     \
        int tyi = __builtin_amdgcn_readlane(__float_as_int(mvC.y), lanem);     \
        float target = __int_as_float((tag & 1) ? tyi : txi);                  \
        v2f col = *(const v2f*)&tT[tag * 130 + 2 * l];                         \
        v2f sv = aP + col;                 /* bit-exact phase-1 adds */        \
        bool h0 = (sv.x == target), h1 = (sv.y == target);                     \
        unsigned long long mask = __ballot(h0 || h1);                          \
        int first = __ffsll(mask) - 1;     /* lowest matching lane */          \
        int cand = h0 ? (2 * l) : (2 * l + 1);                                 \
        tag = __builtin_amdgcn_readlane(cand, first);                          \
        if (l == 0) tagsf[tp] = (float)tag;                                    \
        mvC = MV;                                                              \
      }

      // main loop: 8 steps per group, all tp>=1, refill stage p with time t-9
      while (t >= 9) {
#define MAIN_PHASE(P)                                                          \
        STEP_BODY(lg##P, mv##P, false)                                         \
        { int sN = t - 9; int sc_ = sN < 0 ? 0 : sN;                           \
          lg##P = *(const v2f*)&gb[(size_t)sc_ * KK];                          \
          mv##P = *(const v2f*)&mb[(size_t)sc_ * KK]; }                        \
        --t;
        MAIN_PHASE(0) MAIN_PHASE(1) MAIN_PHASE(2) MAIN_PHASE(3)
        MAIN_PHASE(4) MAIN_PHASE(5) MAIN_PHASE(6) MAIN_PHASE(7)
#undef MAIN_PHASE
      }

      // epilogue: <=8 remaining steps, direct loads, tp==0 guard
      while (t >= 1) {
        const int tp = t - 1;
        int sc_ = tp < 1 ? 0 : tp;
        v2f lgE = *(const v2f*)&gb[(size_t)tp * KK];
        v2f mvE = *(const v2f*)&mb[(size_t)sc_ * KK];
        STEP_BODY(lgE, mvE, true)
        --t;
      }
#undef STEP_BODY
    }
    // wave-0 local: lgkmcnt ordering handled by compiler on tagsf reads
#pragma unroll
    for (int k = 0; k < 8; ++k)
      pred_out[b * TT + l * 8 + k] = tagsf[l * 8 + k];

  } else {
    // ================= FORWARD (log-norm) — verbatim 438us baseline =========
    const int b = blockIdx.x - BB;
    const int L = seq_lens[b];
    float (*ev)[144] = (float(*)[144])(smem + SM_AV);
    float* wmax = smem + SM_WMAX;
    float* rs   = smem + SM_RS;
    float* rsc  = smem + SM_RSC;

    v2f tw[16];
#pragma unroll
    for (int ii = 0; ii < 16; ++ii) {
      v2f tr = *(const v2f*)&trans[(i0 + ii) * KK + j0];
      tw[ii].x = __expf(tr.x);
      tw[ii].y = __expf(tr.y);
    }
    if (tid < KK) ev[0][AIDX(tid)] = __expf(logits[(b * TT) * KK + tid]);
    if (tid < 16) wmax[tid] = 1.0f;

    v2f emC[4], emN[4];
#pragma unroll
    for (int s = 0; s < 4; ++s) {
      int t2 = 1 + s; if (t2 > L - 1) t2 = (L > 1) ? (L - 1) : 0;
      emC[s] = *(const v2f*)&logits[(b * TT + t2) * KK + j0];
    }
    __syncthreads();

    float Cln = 0.0f;
    for (int tc = 1; tc < L; tc += 4) {
#pragma unroll
      for (int s = 0; s < 4; ++s) {
        int t2 = tc + 4 + s; if (t2 > L - 1) t2 = L - 1;
        emN[s] = *(const v2f*)&logits[(b * TT + t2) * KK + j0];
      }
      // renorm factor (exact pow2), once per 4-step chunk
      float r;
      {
        float4 w0 = *(const float4*)&wmax[0];
        float4 w1 = *(const float4*)&wmax[4];
        float4 w2 = *(const float4*)&wmax[8];
        float4 w3 = *(const float4*)&wmax[12];
        float U = fmaxf(fmaxf(fmaxf(w0.x, w0.y), fmaxf(w0.z, w0.w)),
                        fmaxf(fmaxf(w1.x, w1.y), fmaxf(w1.z, w1.w)));
        U = fmaxf(U, fmaxf(fmaxf(fmaxf(w2.x, w2.y), fmaxf(w2.z, w2.w)),
                           fmaxf(fmaxf(w3.x, w3.y), fmaxf(w3.z, w3.w))));
        int ex = (__float_as_int(U) >> 23) & 255;
        r = __int_as_float((254 - ex) << 23);
        Cln += (float)(ex - 127) * 0.6931471805599453f;
      }
#pragma unroll
      for (int s = 0; s < 4; ++s) {
        const int t = tc + s;
        if (t >= L) break;
        const float4* evr = (const float4*)(ev[(t & 1) ^ 1] + AIDX(i0));
        v2f S2 = {0.0f, 0.0f};
#pragma unroll
        for (int q = 0; q < 4; ++q) {
          float4 e4 = evr[q];
#pragma unroll
          for (int c = 0; c < 4; ++c) {
            float e = (c == 0) ? e4.x : (c == 1) ? e4.y : (c == 2) ? e4.z : e4.w;
            S2 += (v2f){e, e} * tw[q * 4 + c];   // pk_fma
          }
        }
        {
          v2f o;
          o.x = dpp_f<0xB1>(S2.x); o.y = dpp_f<0xB1>(S2.y); S2 += o;
          o.x = dpp_f<0x4E>(S2.x); o.y = dpp_f<0x4E>(S2.y); S2 += o;
          o.x = dpp_f<0x141>(S2.x); o.y = dpp_f<0x141>(S2.y); S2 += o;
        }
        v2f em2 = emC[s];
        float evn0 = S2.x * __expf(em2.x);
        float evn1 = S2.y * __expf(em2.y);
        if (s == 0) { evn0 *= r; evn1 *= r; }
        if (rg == 0)
          *(v2f*)(ev[t & 1] + AIDX(j0)) = (v2f){evn0, evn1};
        if (s == 3) {
          float wm = fmaxf(evn0, evn1);
          wm = fmaxf(wm, dpp_f<0x140>(wm));   // xor8 (values 8-uniform)
          wm = fmaxf(wm, swz16_f(wm));        // xor16
          if ((tid & 31) == 0) wmax[tid >> 5] = wm;
        }
        BARRIER_LGKM();
      }
#pragma unroll
      for (int s = 0; s < 4; ++s) emC[s] = emN[s];
    }

    const float* evf = ev[(L - 1) & 1];
    {
      float ssum = (tid < KK) ? evf[AIDX(tid)] : 0.0f;
#pragma unroll
      for (int mm = 1; mm < 64; mm <<= 1) ssum += __shfl_xor(ssum, mm);
      if ((tid & 63) == 0) rs[tid >> 6] = ssum;
    }
    float sc = 0.0f;
    for (int tt2 = tid; tt2 < L; tt2 += 512) {
      int lab = labels[b * TT + tt2];
      sc += logits[(b * TT + tt2) * KK + lab];
      if (tt2 >= 1) sc += trans[labels[b * TT + tt2 - 1] * KK + lab];
    }
#pragma unroll
    for (int mm = 1; mm < 64; mm <<= 1) sc += __shfl_xor(sc, mm);
    if ((tid & 63) == 0) rsc[tid >> 6] = sc;
    __syncthreads();
    if (tid == 0) {
      float es = rs[0]; float scf = rsc[0];
#pragma unroll
      for (int w = 1; w < 8; ++w) { es += rs[w]; scf += rsc[w]; }
      negll[b] = (Cln + logf(es)) - scf;
    }
  }
}

// ============================================================================
// FALLBACK: verbatim 438us two-block kernel (bp in ws), used if ws too small.
// ============================================================================
__global__ __launch_bounds__(512, 4) void crf_main_fb(
    const float* __restrict__ logits,
    const int* __restrict__ labels,
    const int* __restrict__ seq_lens,
    const float* __restrict__ trans,
    float* __restrict__ pred_out,
    float* __restrict__ negll,
    unsigned char* __restrict__ bp)
{
  const int tid = threadIdx.x;
  const int cg = tid >> 3, rg = tid & 7;
  const int j0 = cg * 2, i0 = rg * 16;

  if (blockIdx.x < BB) {
    const int b = blockIdx.x;
    const int L = seq_lens[b];
    __shared__ __align__(16) float av[2][144];
    __shared__ unsigned char tags[TT];
    __shared__ float rv[8]; __shared__ int ri[8];
    __shared__ int last_s;

    v2f tv[16];
#pragma unroll
    for (int ii = 0; ii < 16; ++ii)
      tv[ii] = *(const v2f*)&trans[(i0 + ii) * KK + j0];

    if (tid < KK) av[0][AIDX(tid)] = logits[(b * TT) * KK + tid];

    v2f emC[4], emN[4];
#pragma unroll
    for (int s = 0; s < 4; ++s) {
      int t2 = 1 + s; if (t2 > L - 1) t2 = (L > 1) ? (L - 1) : 0;
      emC[s] = *(const v2f*)&logits[(b * TT + t2) * KK + j0];
    }
    __syncthreads();

    unsigned int pw0 = 0, pw1 = 0; int pend_c = -1;

    for (int tc = 1; tc < L; tc += 4) {
#pragma unroll
      for (int s = 0; s < 4; ++s) {
        int t2 = tc + 4 + s; if (t2 > L - 1) t2 = L - 1;
        emN[s] = *(const v2f*)&logits[(b * TT + t2) * KK + j0];
      }
      if (pend_c >= 0 && rg == 1) {
        *(uint2*)(bp + (((b << 7) + pend_c) << 9) + (cg << 3)) =
            make_uint2(pw0, pw1);
      }
      unsigned int w0 = 0, w1 = 0;
#pragma unroll
      for (int s = 0; s < 4; ++s) {
        const int t = tc + s;
        if (t >= L) break;
        const float4* avr = (const float4*)(av[(t & 1) ^ 1] + AIDX(i0));
        v2f sv[16];
#pragma unroll
        for (int q = 0; q < 4; ++q) {
          float4 a4 = avr[q];
#pragma unroll
          for (int c = 0; c < 4; ++c) {
            float a = (c == 0) ? a4.x : (c == 1) ? a4.y : (c == 2) ? a4.z : a4.w;
            sv[q * 4 + c] = (v2f){a, a} + tv[q * 4 + c];
          }
        }
        v2f m;
        {
          v2f m0 = __builtin_elementwise_max(sv[0], sv[1]);
          v2f m1 = __builtin_elementwise_max(sv[2], sv[3]);
          v2f m2 = __builtin_elementwise_max(sv[4], sv[5]);
          v2f m3 = __builtin_elementwise_max(sv[6], sv[7]);
          v2f m4 = __builtin_elementwise_max(sv[8], sv[9]);
          v2f m5 = __builtin_elementwise_max(sv[10], sv[11]);
          v2f m6 = __builtin_elementwise_max(sv[12], sv[13]);
          v2f m7 = __builtin_elementwise_max(sv[14], sv[15]);
          m0 = __builtin_elementwise_max(m0, m1);
          m2 = __builtin_elementwise_max(m2, m3);
          m4 = __builtin_elementwise_max(m4, m5);
          m6 = __builtin_elementwise_max(m6, m7);
          m0 = __builtin_elementwise_max(m0, m2);
          m4 = __builtin_elementwise_max(m4, m6);
          m = __builtin_elementwise_max(m0, m4);
        }
        {
          v2f o;
          o.x = dpp_f<0xB1>(m.x); o.y = dpp_f<0xB1>(m.y);
          m = __builtin_elementwise_max(m, o);
          o.x = dpp_f<0x4E>(m.x); o.y = dpp_f<0x4E>(m.y);
          m = __builtin_elementwise_max(m, o);
          o.x = dpp_f<0x141>(m.x); o.y = dpp_f<0x141>(m.y);
          m = __builtin_elementwise_max(m, o);
        }
        int ai0 = 0xFFFF, ai1 = 0xFFFF;
#pragma unroll
        for (int i = 15; i >= 0; --i) {
          ai0 = (sv[i].x == m.x) ? (i0 + i) : ai0;
          ai1 = (sv[i].y == m.y) ? (i0 + i) : ai1;
        }
        int aip = ai0 | (ai1 << 16);
        aip = pkminu16(aip, dpp_i<0xB1>(aip));
        aip = pkminu16(aip, dpp_i<0x4E>(aip));
        aip = pkminu16(aip, dpp_i<0x141>(aip));

        v2f em2 = emC[s];
        if (rg == 0)
          *(v2f*)(av[t & 1] + AIDX(j0)) = m + em2;
        unsigned int pk = ((unsigned int)aip & 0xFFu) |
                          (((unsigned int)aip >> 8) & 0xFF00u);
        unsigned int sh = pk << ((s & 1) * 16);
        if (s < 2) w0 |= sh; else w1 |= sh;
        BARRIER_LGKM();
      }
      pw0 = w0; pw1 = w1; pend_c = (tc - 1) >> 2;
#pragma unroll
      for (int s = 0; s < 4; ++s) emC[s] = emN[s];
    }
    if (pend_c >= 0 && rg == 1) {
      *(uint2*)(bp + (((b << 7) + pend_c) << 9) + (cg << 3)) =
          make_uint2(pw0, pw1);
    }

    const float* avf = av[(L - 1) & 1];
    {
      float v = (tid < KK) ? avf[AIDX(tid)] : -3.4e38f;
      int idx = (tid < KK) ? tid : KK;
#pragma unroll
      for (int mm = 1; mm < 64; mm <<= 1) {
        float ov = __shfl_xor(v, mm);
        int oi = __shfl_xor(idx, mm);
        if (ov > v || (ov == v && oi < idx)) { v = ov; idx = oi; }
      }
      if ((tid & 63) == 0) { rv[tid >> 6] = v; ri[tid >> 6] = idx; }
    }
    __syncthreads();
    if (tid == 0) {
      float bv = rv[0]; int bi = ri[0];
#pragma unroll
      for (int w = 1; w < 8; ++w)
        if (rv[w] > bv || (rv[w] == bv && ri[w] < bi)) { bv = rv[w]; bi = ri[w]; }
      last_s = bi;
    }
    __syncthreads();
    const int last = last_s;
    if (tid >= L - 1 && tid < TT) tags[tid] = (unsigned char)last;
    __syncthreads();

    if (tid < 64 && L >= 2) {
      const uint2* bpv = (const uint2*)bp;
      int tag = last;
      int cTop = (L - 2) >> 2;
      uint2 q = bpv[(((b << 7) + cTop) << 6) + tid];
      for (int c = cTop; c >= 0; --c) {
        uint2 qn;
        if (c > 0) qn = bpv[(((b << 7) + (c - 1)) << 6) + tid];
        int sHi = (L - 2) - 4 * c; if (sHi > 3) sHi = 3;
#pragma unroll
        for (int s = 3; s >= 0; --s) {
          if (s <= sHi) {
            int word = (s < 2) ? (int)q.x : (int)q.y;
            unsigned int w = (unsigned int)__shfl(word, tag >> 1);
            tag = (int)((w >> ((((s & 1) << 1) | (tag & 1)) << 3)) & 255u);
            if (tid == 0) tags[4 * c + s] = (unsigned char)tag;
          }
        }
        q = qn;
      }
    }
    __syncthreads();
    pred_out[b * TT + tid] = (float)tags[tid];

  } else {
    const int b = blockIdx.x - BB;
    const int L = seq_lens[b];
    __shared__ __align__(16) float ev[2][144];
    __shared__ __align__(16) float wmax[16];
    __shared__ float rs[8]; __shared__ float rsc[8];

    v2f tw[16];
#pragma unroll
    for (int ii = 0; ii < 16; ++ii) {
      v2f tr = *(const v2f*)&trans[(i0 + ii) * KK + j0];
      tw[ii].x = __expf(tr.x);
      tw[ii].y = __expf(tr.y);
    }
    if (tid < KK) ev[0][AIDX(tid)] = __expf(logits[(b * TT) * KK + tid]);
    if (tid < 16) wmax[tid] = 1.0f;

    v2f emC[4], emN[4];
#pragma unroll
    for (int s = 0; s < 4; ++s) {
      int t2 = 1 + s; if (t2 > L - 1) t2 = (L > 1) ? (L - 1) : 0;
      emC[s] = *(const v2f*)&logits[(b * TT + t2) * KK + j0];
    }
    __syncthreads();

    float Cln = 0.0f;
    for (int tc = 1; tc < L; tc += 4) {
#pragma unroll
      for (int s = 0; s < 4; ++s) {
        int t2 = tc + 4 + s; if (t2 > L - 1) t2 = L - 1;
        emN[s] = *(const v2f*)&logits[(b * TT + t2) * KK + j0];
      }
      float r;
      {
        float4 w0 = *(const float4*)&wmax[0];
        float4 w1 = *(const float4*)&wmax[4];
        float4 w2 = *(const float4*)&wmax[8];
        float4 w3 = *(const float4*)&wmax[12];
        float U = fmaxf(fmaxf(fmaxf(w0.x, w0.y), fmaxf(w0.z, w0.w)),
                        fmaxf(fmaxf(w1.x, w1.y), fmaxf(w1.z, w1.w)));
        U = fmaxf(U, fmaxf(fmaxf(fmaxf(w2.x, w2.y), fmaxf(w2.z, w2.w)),
                           fmaxf(fmaxf(w3.x, w3.y), fmaxf(w3.z, w3.w))));
        int ex = (__float_as_int(U) >> 23) & 255;
        r = __int_as_float((254 - ex) << 23);
        Cln += (float)(ex - 127) * 0.6931471805599453f;
      }
#pragma unroll
      for (int s = 0; s < 4; ++s) {
        const int t = tc + s;
        if (t >= L) break;
        const float4* evr = (const float4*)(ev[(t & 1) ^ 1] + AIDX(i0));
        v2f S2 = {0.0f, 0.0f};
#pragma unroll
        for (int q = 0; q < 4; ++q) {
          float4 e4 = evr[q];
#pragma unroll
          for (int c = 0; c < 4; ++c) {
            float e = (c == 0) ? e4.x : (c == 1) ? e4.y : (c == 2) ? e4.z : e4.w;
            S2 += (v2f){e, e} * tw[q * 4 + c];
          }
        }
        {
          v2f o;
          o.x = dpp_f<0xB1>(S2.x); o.y = dpp_f<0xB1>(S2.y); S2 += o;
          o.x = dpp_f<0x4E>(S2.x); o.y = dpp_f<0x4E>(S2.y); S2 += o;
          o.x = dpp_f<0x141>(S2.x); o.y = dpp_f<0x141>(S2.y); S2 += o;
        }
        v2f em2 = emC[s];
        float evn0 = S2.x * __expf(em2.x);
        float evn1 = S2.y * __expf(em2.y);
        if (s == 0) { evn0 *= r; evn1 *= r; }
        if (rg == 0)
          *(v2f*)(ev[t & 1] + AIDX(j0)) = (v2f){evn0, evn1};
        if (s == 3) {
          float wm = fmaxf(evn0, evn1);
          wm = fmaxf(wm, dpp_f<0x140>(wm));
          wm = fmaxf(wm, swz16_f(wm));
          if ((tid & 31) == 0) wmax[tid >> 5] = wm;
        }
        BARRIER_LGKM();
      }
#pragma unroll
      for (int s = 0; s < 4; ++s) emC[s] = emN[s];
    }

    const float* evf = ev[(L - 1) & 1];
    {
      float ssum = (tid < KK) ? evf[AIDX(tid)] : 0.0f;
#pragma unroll
      for (int mm = 1; mm < 64; mm <<= 1) ssum += __shfl_xor(ssum, mm);
      if ((tid & 63) == 0) rs[tid >> 6] = ssum;
    }
    float sc = 0.0f;
    for (int tt2 = tid; tt2 < L; tt2 += 512) {
      int lab = labels[b * TT + tt2];
      sc += logits[(b * TT + tt2) * KK + lab];
      if (tt2 >= 1) sc += trans[labels[b * TT + tt2 - 1] * KK + lab];
    }
#pragma unroll
    for (int mm = 1; mm < 64; mm <<= 1) sc += __shfl_xor(sc, mm);
    if ((tid & 63) == 0) rsc[tid >> 6] = sc;
    __syncthreads();
    if (tid == 0) {
      float es = rs[0]; float scf = rsc[0];
#pragma unroll
      for (int w = 1; w < 8; ++w) { es += rs[w]; scf += rsc[w]; }
      negll[b] = (Cln + logf(es)) - scf;
    }
  }
}

__global__ void crf_loss_reduce(const float* __restrict__ negll, float* __restrict__ out) {
  int tid = threadIdx.x;
  float v = negll[tid];
#pragma unroll
  for (int m = 1; m < 64; m <<= 1) v += __shfl_xor(v, m);
  __shared__ float p[4];
  if ((tid & 63) == 0) p[tid >> 6] = v;
  __syncthreads();
  if (tid == 0) out[0] = p[0] + p[1] + p[2] + p[3];
}

extern "C" void kernel_launch(void* const* d_in, const int* in_sizes, int n_in,
                              void* d_out, int out_size, void* d_ws, size_t ws_size,
                              hipStream_t stream) {
  const float* logits   = (const float*)d_in[0];
  const int*   labels   = (const int*)d_in[1];
  const int*   seq_lens = (const int*)d_in[2];
  const float* trans    = (const float*)d_in[3];
  float* out = (float*)d_out;

  float* negll = (float*)d_ws;                          // [0, 1KB): 256 floats
  const size_t M_OFF = 4096;
  const size_t NEED = M_OFF + (size_t)BB * TT * KK * 4;   // ~67.1 MB

  if (ws_size >= NEED) {
    float* mOut = (float*)((char*)d_ws + M_OFF);        // [4KB, 4KB+67.1MB)
    crf_main<<<2 * BB, 512, 0, stream>>>(logits, labels, seq_lens, trans,
                                         out + 1, negll, mOut);
  } else {
    unsigned char* bp = (unsigned char*)d_ws + 1024;    // 16.8 MB
    crf_main_fb<<<2 * BB, 512, 0, stream>>>(logits, labels, seq_lens, trans,
                                            out + 1, negll, bp);
  }
  crf_loss_reduce<<<1, 256, 0, stream>>>(negll, out);
}